// Round 16
// baseline (681.451 us; speedup 1.0000x reference)
//
#include <hip/hip_runtime.h>
#include <hip/hip_bf16.h>

#define T_TOK 3072
#define HIDDEN 2048
#define NHQ 16
#define NHKV 8
#define DH 128
#define WINDOW 1024
#define KVN 1024

typedef __attribute__((ext_vector_type(4))) float f32x4;
typedef __attribute__((ext_vector_type(8))) short bf16x8;
typedef __attribute__((ext_vector_type(8))) unsigned short ushort8;
typedef __attribute__((ext_vector_type(4))) unsigned short ushort4v;

__device__ __forceinline__ unsigned short f2bf(float f) {
  union { float fv; unsigned u; } v; v.fv = f;
  unsigned r = v.u + 0x7fffu + ((v.u >> 16) & 1u);
  return (unsigned short)(r >> 16);
}
__device__ __forceinline__ float bf2f(unsigned short h) {
  union { unsigned u; float f; } v; v.u = ((unsigned)h) << 16;
  return v.f;
}
__device__ __forceinline__ void split2(float f, unsigned short& hi, unsigned short& lo) {
  hi = f2bf(f);
  lo = f2bf(f - bf2f(hi));
}

// ---------------- mega-prep: ALL independent input preprocessing in ONE launch ----------------
// blocks [0,6144):       cvt_split hidden -> xh/xl
// blocks [6144,14336):   transpose wq0/wk0/wv0 -> fused QKV Bt (hi/lo)
// blocks [14336,18432):  cvt_split wo0 -> wo0s (row-major hi/lo)
// blocks [18432,22528):  transpose wq1 -> wq1t (hi/lo)
// blocks [22528,26624):  transpose wo1 -> wo1t (hi only)
__global__ __launch_bounds__(256) void prep(const float* __restrict__ hidden,
                                            const float* __restrict__ wq0,
                                            const float* __restrict__ wk0,
                                            const float* __restrict__ wv0,
                                            const float* __restrict__ wo0,
                                            const float* __restrict__ wq1,
                                            const float* __restrict__ wo1,
                                            unsigned short* __restrict__ xh,
                                            unsigned short* __restrict__ xl,
                                            unsigned short* __restrict__ wqkvh,
                                            unsigned short* __restrict__ wqkvl,
                                            unsigned short* __restrict__ wo0sh,
                                            unsigned short* __restrict__ wo0sl,
                                            unsigned short* __restrict__ wq1th,
                                            unsigned short* __restrict__ wq1tl,
                                            unsigned short* __restrict__ wo1th) {
  __shared__ float tile[32][33];
  const int K = HIDDEN;
  int id = blockIdx.x;
  if (id < 6144 || (id >= 14336 && id < 18432)) {
    const float* src; unsigned short *dh, *dl; int local;
    if (id < 6144) { src = hidden; dh = xh; dl = xl; local = id; }
    else           { src = wo0; dh = wo0sh; dl = wo0sl; local = id - 14336; }
    int i = (local * 256 + threadIdx.x) * 4;
    f32x4 v = *(const f32x4*)(src + i);
    ushort4v oh, ol;
#pragma unroll
    for (int j = 0; j < 4; ++j) {
      unsigned short h, l;
      split2(v[j], h, l);
      oh[j] = h; ol[j] = l;
    }
    *(ushort4v*)(dh + i) = oh;
    *(ushort4v*)(dl + i) = ol;
    return;
  }
  const float* W; int N, local; unsigned short *Dh, *Dl; size_t dstoff;
  if (id < 14336) {
    int lid = id - 6144;
    if (lid < 4096)      { W = wq0; N = 2048; local = lid;        dstoff = 0; }
    else if (lid < 6144) { W = wk0; N = 1024; local = lid - 4096; dstoff = (size_t)2048 * K; }
    else                 { W = wv0; N = 1024; local = lid - 6144; dstoff = (size_t)3072 * K; }
    Dh = wqkvh; Dl = wqkvl;
  } else if (id < 22528) {
    W = wq1; N = 2048; local = id - 18432; dstoff = 0;
    Dh = wq1th; Dl = wq1tl;
  } else {
    W = wo1; N = 2048; local = id - 22528; dstoff = 0;
    Dh = wo1th; Dl = nullptr;
  }
  int ntc = N / 32;
  int bn = (local % ntc) * 32, bk = (local / ntc) * 32;
  int tx = threadIdx.x & 31, ty = threadIdx.x >> 5;
#pragma unroll
  for (int i = 0; i < 4; ++i)
    tile[ty + i * 8][tx] = W[(size_t)(bk + ty + i * 8) * N + bn + tx];
  __syncthreads();
#pragma unroll
  for (int i = 0; i < 4; ++i) {
    unsigned short h, l;
    split2(tile[tx][ty + i * 8], h, l);
    Dh[dstoff + (size_t)(bn + ty + i * 8) * K + bk + tx] = h;
    if (Dl) Dl[dstoff + (size_t)(bn + ty + i * 8) * K + bk + tx] = l;
  }
}

// ---------------- generic u16 transpose ----------------
__global__ __launch_bounds__(256) void transpose_u16(const unsigned short* __restrict__ src,
                                                     unsigned short* __restrict__ dst,
                                                     int R, int C) {
  __shared__ unsigned short tile[32][33];
  int bc = blockIdx.x * 32, br = blockIdx.y * 32;
  int tx = threadIdx.x & 31, ty = threadIdx.x >> 5;
#pragma unroll
  for (int i = 0; i < 4; ++i)
    tile[ty + i * 8][tx] = src[(size_t)(br + ty + i * 8) * C + bc + tx];
  __syncthreads();
#pragma unroll
  for (int i = 0; i < 4; ++i)
    dst[(size_t)(bc + ty + i * 8) * R + br + tx] = tile[tx][ty + i * 8];
}

#define GSLOT(lane) ((((lane) & 3) + 4 - (((lane) >> 3) & 3)) & 3)

// ---------------- QKV 3-term GEMM, 128x128 tile, dual fp32 out ----------------
// N must be 4096. bn interleave (bn = (bnr&3)*8 + bnr>>2) gives each XCD one
// V-slot; V-blocks (bn>=24, cols 3072..4095) run 1-term (V is hi-only downstream).
__global__ __launch_bounds__(256) void gemm3_qkv(const unsigned short* __restrict__ Ah,
                                                 const unsigned short* __restrict__ Al,
                                                 const unsigned short* __restrict__ Bh,
                                                 const unsigned short* __restrict__ Bl,
                                                 float* __restrict__ Cq,
                                                 float* __restrict__ Ckv,
                                                 int strd, int M, int N, int K) {
  __shared__ unsigned short ah_lds[128 * 32];
  __shared__ unsigned short al_lds[128 * 32];
  __shared__ unsigned short bh_lds[128 * 32];
  __shared__ unsigned short bl_lds[128 * 32];
  const int tid = threadIdx.x, lane = tid & 63, wave = tid >> 6;
  const int wr = (wave >> 1) * 64, wc = (wave & 1) * 64;
  const int g = lane >> 4, r16 = lane & 15;
  int nwg = gridDim.x * gridDim.y;
  int id = blockIdx.y * gridDim.x + blockIdx.x;
  int nid = (id & 7) * (nwg >> 3) + (id >> 3);
  const int bm = nid % gridDim.x;
  const int bnr = nid / gridDim.x;
  const int bn = ((bnr & 3) << 3) + (bnr >> 2);
  const bool light = (bn >= 24);  // V region: 1-term only
  f32x4 acc[4][4];
#pragma unroll
  for (int i = 0; i < 4; ++i)
#pragma unroll
    for (int j = 0; j < 4; ++j) acc[i][j] = (f32x4){0.f, 0.f, 0.f, 0.f};

  const unsigned short* AhB = Ah + (size_t)bm * 128 * K;
  const unsigned short* AlB = Al + (size_t)bm * 128 * K;
  const unsigned short* BhB = Bh + (size_t)bn * 128 * K;
  const unsigned short* BlB = Bl + (size_t)bn * 128 * K;

  const int slg = GSLOT(lane) * 8;
  const int sr = ((r16 >> 1) & 3);

  for (int kt = 0; kt < K; kt += 32) {
    __syncthreads();
#pragma unroll
    for (int c = 0; c < 2; ++c) {
      size_t goff = (size_t)(wave * 32 + c * 16 + (lane >> 2)) * K + kt + slg;
      int loff = (wave * 2 + c) * 512;
      __builtin_amdgcn_global_load_lds(
          (const __attribute__((address_space(1))) unsigned int*)(AhB + goff),
          (__attribute__((address_space(3))) unsigned int*)(ah_lds + loff), 16, 0, 0);
      __builtin_amdgcn_global_load_lds(
          (const __attribute__((address_space(1))) unsigned int*)(AlB + goff),
          (__attribute__((address_space(3))) unsigned int*)(al_lds + loff), 16, 0, 0);
      __builtin_amdgcn_global_load_lds(
          (const __attribute__((address_space(1))) unsigned int*)(BhB + goff),
          (__attribute__((address_space(3))) unsigned int*)(bh_lds + loff), 16, 0, 0);
      __builtin_amdgcn_global_load_lds(
          (const __attribute__((address_space(1))) unsigned int*)(BlB + goff),
          (__attribute__((address_space(3))) unsigned int*)(bl_lds + loff), 16, 0, 0);
    }
    __syncthreads();
    bf16x8 ahf[4], alf[4], bhf[4], blf[4];
    int sa = ((g + sr) & 3) * 8;
#pragma unroll
    for (int i = 0; i < 4; ++i) {
      ahf[i] = *(const bf16x8*)&ah_lds[(wr + i * 16 + r16) * 32 + sa];
      alf[i] = *(const bf16x8*)&al_lds[(wr + i * 16 + r16) * 32 + sa];
      bhf[i] = *(const bf16x8*)&bh_lds[(wc + i * 16 + r16) * 32 + sa];
      blf[i] = *(const bf16x8*)&bl_lds[(wc + i * 16 + r16) * 32 + sa];
    }
    if (light) {
#pragma unroll
      for (int i = 0; i < 4; ++i)
#pragma unroll
        for (int j = 0; j < 4; ++j)
          acc[i][j] = __builtin_amdgcn_mfma_f32_16x16x32_bf16(ahf[i], bhf[j], acc[i][j], 0, 0, 0);
    } else {
#pragma unroll
      for (int i = 0; i < 4; ++i)
#pragma unroll
        for (int j = 0; j < 4; ++j) {
          acc[i][j] = __builtin_amdgcn_mfma_f32_16x16x32_bf16(ahf[i], bhf[j], acc[i][j], 0, 0, 0);
          acc[i][j] = __builtin_amdgcn_mfma_f32_16x16x32_bf16(ahf[i], blf[j], acc[i][j], 0, 0, 0);
          acc[i][j] = __builtin_amdgcn_mfma_f32_16x16x32_bf16(alf[i], bhf[j], acc[i][j], 0, 0, 0);
        }
    }
  }

#pragma unroll
  for (int i = 0; i < 4; ++i) {
    int row = bm * 128 + wr + i * 16 + g * 4;
#pragma unroll
    for (int j = 0; j < 4; ++j) {
      int colg = bn * 128 + wc + j * 16 + r16;
      float* Cb; int cc;
      if (colg < 2048) { Cb = Cq; cc = colg; } else { Cb = Ckv; cc = colg - 2048; }
#pragma unroll
      for (int r = 0; r < 4; ++r)
        Cb[(size_t)(row + r) * strd + cc] = acc[i][j][r];
    }
  }
}

// ---------------- 3-term split GEMM, 64x128 tile, hi/lo bf16 out (W01) ----------------
__global__ __launch_bounds__(256) void gemm3_64(const unsigned short* __restrict__ Ah,
                                                const unsigned short* __restrict__ Al,
                                                const unsigned short* __restrict__ Bh,
                                                const unsigned short* __restrict__ Bl,
                                                unsigned short* __restrict__ Ch,
                                                unsigned short* __restrict__ Cl,
                                                int M, int N, int K) {
  __shared__ unsigned short ah_lds[64 * 32];
  __shared__ unsigned short al_lds[64 * 32];
  __shared__ unsigned short bh_lds[128 * 32];
  __shared__ unsigned short bl_lds[128 * 32];
  const int tid = threadIdx.x, lane = tid & 63, wave = tid >> 6;
  const int wr = (wave >> 1) * 32, wc = (wave & 1) * 64;
  const int g = lane >> 4, r16 = lane & 15;
  int nwg = gridDim.x * gridDim.y;
  int id = blockIdx.y * gridDim.x + blockIdx.x;
  int nid = (id & 7) * (nwg >> 3) + (id >> 3);
  const int bm = nid % gridDim.x, bn = nid / gridDim.x;
  f32x4 acc[2][4];
#pragma unroll
  for (int i = 0; i < 2; ++i)
#pragma unroll
    for (int j = 0; j < 4; ++j) acc[i][j] = (f32x4){0.f, 0.f, 0.f, 0.f};

  const unsigned short* AhB = Ah + (size_t)bm * 64 * K;
  const unsigned short* AlB = Al + (size_t)bm * 64 * K;
  const unsigned short* BhB = Bh + (size_t)bn * 128 * K;
  const unsigned short* BlB = Bl + (size_t)bn * 128 * K;

  const int slg = GSLOT(lane) * 8;
  const int sr = ((r16 >> 1) & 3);

  for (int kt = 0; kt < K; kt += 32) {
    __syncthreads();
    {
      size_t goff = (size_t)(wave * 16 + (lane >> 2)) * K + kt + slg;
      __builtin_amdgcn_global_load_lds(
          (const __attribute__((address_space(1))) unsigned int*)(AhB + goff),
          (__attribute__((address_space(3))) unsigned int*)(ah_lds + wave * 512), 16, 0, 0);
      __builtin_amdgcn_global_load_lds(
          (const __attribute__((address_space(1))) unsigned int*)(AlB + goff),
          (__attribute__((address_space(3))) unsigned int*)(al_lds + wave * 512), 16, 0, 0);
    }
#pragma unroll
    for (int c = 0; c < 2; ++c) {
      size_t goff = (size_t)(wave * 32 + c * 16 + (lane >> 2)) * K + kt + slg;
      int loff = (wave * 2 + c) * 512;
      __builtin_amdgcn_global_load_lds(
          (const __attribute__((address_space(1))) unsigned int*)(BhB + goff),
          (__attribute__((address_space(3))) unsigned int*)(bh_lds + loff), 16, 0, 0);
      __builtin_amdgcn_global_load_lds(
          (const __attribute__((address_space(1))) unsigned int*)(BlB + goff),
          (__attribute__((address_space(3))) unsigned int*)(bl_lds + loff), 16, 0, 0);
    }
    __syncthreads();
    bf16x8 ahf[2], alf[2], bhf[4], blf[4];
    int sa = ((g + sr) & 3) * 8;
#pragma unroll
    for (int i = 0; i < 2; ++i) {
      ahf[i] = *(const bf16x8*)&ah_lds[(wr + i * 16 + r16) * 32 + sa];
      alf[i] = *(const bf16x8*)&al_lds[(wr + i * 16 + r16) * 32 + sa];
    }
#pragma unroll
    for (int j = 0; j < 4; ++j) {
      bhf[j] = *(const bf16x8*)&bh_lds[(wc + j * 16 + r16) * 32 + sa];
      blf[j] = *(const bf16x8*)&bl_lds[(wc + j * 16 + r16) * 32 + sa];
    }
#pragma unroll
    for (int i = 0; i < 2; ++i)
#pragma unroll
      for (int j = 0; j < 4; ++j) {
        acc[i][j] = __builtin_amdgcn_mfma_f32_16x16x32_bf16(ahf[i], bhf[j], acc[i][j], 0, 0, 0);
        acc[i][j] = __builtin_amdgcn_mfma_f32_16x16x32_bf16(ahf[i], blf[j], acc[i][j], 0, 0, 0);
        acc[i][j] = __builtin_amdgcn_mfma_f32_16x16x32_bf16(alf[i], bhf[j], acc[i][j], 0, 0, 0);
      }
  }

#pragma unroll
  for (int i = 0; i < 2; ++i) {
    int row = bm * 64 + wr + i * 16 + g * 4;
#pragma unroll
    for (int j = 0; j < 4; ++j) {
      int col = bn * 128 + wc + j * 16 + r16;
#pragma unroll
      for (int r = 0; r < 4; ++r) {
        unsigned short h, l;
        split2(acc[i][j][r], h, l);
        Ch[(size_t)(row + r) * N + col] = h;
        Cl[(size_t)(row + r) * N + col] = l;
      }
    }
  }
}

// ---------------- 3-term split GEMM, 96x128 tile (fp32 out) ----------------
__global__ __launch_bounds__(256) void gemm3_96(const unsigned short* __restrict__ Ah,
                                                const unsigned short* __restrict__ Al,
                                                const unsigned short* __restrict__ Bh,
                                                const unsigned short* __restrict__ Bl,
                                                float* __restrict__ Cf,
                                                int M, int N, int K) {
  __shared__ unsigned short ah_lds[96 * 32];
  __shared__ unsigned short al_lds[96 * 32];
  __shared__ unsigned short bh_lds[128 * 32];
  __shared__ unsigned short bl_lds[128 * 32];
  const int tid = threadIdx.x, lane = tid & 63, wave = tid >> 6;
  const int wr = (wave >> 1) * 48, wc = (wave & 1) * 64;
  const int g = lane >> 4, r16 = lane & 15;
  int nwg = gridDim.x * gridDim.y;
  int id = blockIdx.y * gridDim.x + blockIdx.x;
  int nid = (id & 7) * (nwg >> 3) + (id >> 3);
  const int bm = nid % gridDim.x, bn = nid / gridDim.x;
  f32x4 acc[3][4];
#pragma unroll
  for (int i = 0; i < 3; ++i)
#pragma unroll
    for (int j = 0; j < 4; ++j) acc[i][j] = (f32x4){0.f, 0.f, 0.f, 0.f};

  const unsigned short* AhB = Ah + (size_t)bm * 96 * K;
  const unsigned short* AlB = Al + (size_t)bm * 96 * K;
  const unsigned short* BhB = Bh + (size_t)bn * 128 * K;
  const unsigned short* BlB = Bl + (size_t)bn * 128 * K;

  const int slg = GSLOT(lane) * 8;
  const int sr = ((r16 >> 1) & 3);

  for (int kt = 0; kt < K; kt += 32) {
    __syncthreads();
    {
      int c = wave;
      size_t goff = (size_t)(c * 16 + (lane >> 2)) * K + kt + slg;
      __builtin_amdgcn_global_load_lds(
          (const __attribute__((address_space(1))) unsigned int*)(AhB + goff),
          (__attribute__((address_space(3))) unsigned int*)(ah_lds + c * 512), 16, 0, 0);
      __builtin_amdgcn_global_load_lds(
          (const __attribute__((address_space(1))) unsigned int*)(AlB + goff),
          (__attribute__((address_space(3))) unsigned int*)(al_lds + c * 512), 16, 0, 0);
      if (wave < 2) {
        int c2 = 4 + wave;
        size_t goff2 = (size_t)(c2 * 16 + (lane >> 2)) * K + kt + slg;
        __builtin_amdgcn_global_load_lds(
            (const __attribute__((address_space(1))) unsigned int*)(AhB + goff2),
            (__attribute__((address_space(3))) unsigned int*)(ah_lds + c2 * 512), 16, 0, 0);
        __builtin_amdgcn_global_load_lds(
            (const __attribute__((address_space(1))) unsigned int*)(AlB + goff2),
            (__attribute__((address_space(3))) unsigned int*)(al_lds + c2 * 512), 16, 0, 0);
      }
    }
#pragma unroll
    for (int c = 0; c < 2; ++c) {
      size_t goff = (size_t)(wave * 32 + c * 16 + (lane >> 2)) * K + kt + slg;
      int loff = (wave * 2 + c) * 512;
      __builtin_amdgcn_global_load_lds(
          (const __attribute__((address_space(1))) unsigned int*)(BhB + goff),
          (__attribute__((address_space(3))) unsigned int*)(bh_lds + loff), 16, 0, 0);
      __builtin_amdgcn_global_load_lds(
          (const __attribute__((address_space(1))) unsigned int*)(BlB + goff),
          (__attribute__((address_space(3))) unsigned int*)(bl_lds + loff), 16, 0, 0);
    }
    __syncthreads();
    bf16x8 ahf[3], alf[3], bhf[4], blf[4];
    int sa = ((g + sr) & 3) * 8;
#pragma unroll
    for (int i = 0; i < 3; ++i) {
      ahf[i] = *(const bf16x8*)&ah_lds[(wr + i * 16 + r16) * 32 + sa];
      alf[i] = *(const bf16x8*)&al_lds[(wr + i * 16 + r16) * 32 + sa];
    }
#pragma unroll
    for (int j = 0; j < 4; ++j) {
      bhf[j] = *(const bf16x8*)&bh_lds[(wc + j * 16 + r16) * 32 + sa];
      blf[j] = *(const bf16x8*)&bl_lds[(wc + j * 16 + r16) * 32 + sa];
    }
#pragma unroll
    for (int i = 0; i < 3; ++i)
#pragma unroll
      for (int j = 0; j < 4; ++j) {
        acc[i][j] = __builtin_amdgcn_mfma_f32_16x16x32_bf16(ahf[i], bhf[j], acc[i][j], 0, 0, 0);
        acc[i][j] = __builtin_amdgcn_mfma_f32_16x16x32_bf16(ahf[i], blf[j], acc[i][j], 0, 0, 0);
        acc[i][j] = __builtin_amdgcn_mfma_f32_16x16x32_bf16(alf[i], bhf[j], acc[i][j], 0, 0, 0);
      }
  }

#pragma unroll
  for (int i = 0; i < 3; ++i) {
    int row = bm * 96 + wr + i * 16 + g * 4;
#pragma unroll
    for (int j = 0; j < 4; ++j) {
      int col = bn * 128 + wc + j * 16 + r16;
#pragma unroll
      for (int r = 0; r < 4; ++r)
        Cf[(size_t)(row + r) * N + col] = acc[i][j][r];
    }
  }
}

// ---------------- 1-term bf16 GEMM, 96x128 tile ----------------
__global__ __launch_bounds__(256) void gemm1_96(const unsigned short* __restrict__ Ah,
                                                const unsigned short* __restrict__ Bh,
                                                float* __restrict__ Cf,
                                                int M, int N, int K) {
  __shared__ unsigned short ah_lds[96 * 32];
  __shared__ unsigned short bh_lds[128 * 32];
  const int tid = threadIdx.x, lane = tid & 63, wave = tid >> 6;
  const int wr = (wave >> 1) * 48, wc = (wave & 1) * 64;
  const int g = lane >> 4, r16 = lane & 15;
  int nwg = gridDim.x * gridDim.y;
  int id = blockIdx.y * gridDim.x + blockIdx.x;
  int nid = (id & 7) * (nwg >> 3) + (id >> 3);
  const int bm = nid % gridDim.x, bn = nid / gridDim.x;
  f32x4 acc[3][4];
#pragma unroll
  for (int i = 0; i < 3; ++i)
#pragma unroll
    for (int j = 0; j < 4; ++j) acc[i][j] = (f32x4){0.f, 0.f, 0.f, 0.f};

  const unsigned short* AhB = Ah + (size_t)bm * 96 * K;
  const unsigned short* BhB = Bh + (size_t)bn * 128 * K;

  const int slg = GSLOT(lane) * 8;
  const int sr = ((r16 >> 1) & 3);

  for (int kt = 0; kt < K; kt += 32) {
    __syncthreads();
    {
      int c = wave;
      size_t goff = (size_t)(c * 16 + (lane >> 2)) * K + kt + slg;
      __builtin_amdgcn_global_load_lds(
          (const __attribute__((address_space(1))) unsigned int*)(AhB + goff),
          (__attribute__((address_space(3))) unsigned int*)(ah_lds + c * 512), 16, 0, 0);
      if (wave < 2) {
        int c2 = 4 + wave;
        size_t goff2 = (size_t)(c2 * 16 + (lane >> 2)) * K + kt + slg;
        __builtin_amdgcn_global_load_lds(
            (const __attribute__((address_space(1))) unsigned int*)(AhB + goff2),
            (__attribute__((address_space(3))) unsigned int*)(ah_lds + c2 * 512), 16, 0, 0);
      }
    }
#pragma unroll
    for (int c = 0; c < 2; ++c) {
      size_t goff = (size_t)(wave * 32 + c * 16 + (lane >> 2)) * K + kt + slg;
      __builtin_amdgcn_global_load_lds(
          (const __attribute__((address_space(1))) unsigned int*)(BhB + goff),
          (__attribute__((address_space(3))) unsigned int*)(bh_lds + (wave * 2 + c) * 512), 16, 0, 0);
    }
    __syncthreads();
    bf16x8 ahf[3], bhf[4];
    int sa = ((g + sr) & 3) * 8;
#pragma unroll
    for (int i = 0; i < 3; ++i)
      ahf[i] = *(const bf16x8*)&ah_lds[(wr + i * 16 + r16) * 32 + sa];
#pragma unroll
    for (int j = 0; j < 4; ++j)
      bhf[j] = *(const bf16x8*)&bh_lds[(wc + j * 16 + r16) * 32 + sa];
#pragma unroll
    for (int i = 0; i < 3; ++i)
#pragma unroll
      for (int j = 0; j < 4; ++j)
        acc[i][j] = __builtin_amdgcn_mfma_f32_16x16x32_bf16(ahf[i], bhf[j], acc[i][j], 0, 0, 0);
  }

#pragma unroll
  for (int i = 0; i < 3; ++i) {
    int row = bm * 96 + wr + i * 16 + g * 4;
#pragma unroll
    for (int j = 0; j < 4; ++j) {
      int col = bn * 128 + wc + j * 16 + r16;
#pragma unroll
      for (int r = 0; r < 4; ++r)
        Cf[(size_t)(row + r) * N + col] = acc[i][j][r];
    }
  }
}

// ---------------- merged K+V RMSNorm ----------------
__global__ __launch_bounds__(256) void rms_kv(const float* __restrict__ X,
                                              const float* __restrict__ kn,
                                              const float* __restrict__ cosp,
                                              const float* __restrict__ sinp,
                                              unsigned short* __restrict__ kh,
                                              unsigned short* __restrict__ kl,
                                              unsigned short* __restrict__ vh) {
  const int half = T_TOK * NHKV / 4;
  bool isV = (int)blockIdx.x >= half;
  int bid = isV ? blockIdx.x - half : blockIdx.x;
  int row = bid * 4 + (threadIdx.x >> 6);
  int lane = threadIdx.x & 63;
  int t = row >> 3, hh_ = row & 7;
  const float* x = X + (size_t)t * HIDDEN + (isV ? KVN : 0) + (size_t)hh_ * DH;
  float x1 = x[lane], x2 = x[lane + 64];
  float ss = x1 * x1 + x2 * x2;
#pragma unroll
  for (int m = 1; m < 64; m <<= 1) ss += __shfl_xor(ss, m, 64);
  float inv = rsqrtf(ss * (1.0f / 128.0f) + 1e-6f);
  float y1 = x1 * inv, y2 = x2 * inv;
  if (!isV) {
    y1 *= kn[lane]; y2 *= kn[lane + 64];
    float c1 = cosp[t * DH + lane], s1 = sinp[t * DH + lane];
    float c2 = cosp[t * DH + lane + 64], s2 = sinp[t * DH + lane + 64];
    float o1 = y1 * c1 - y2 * s1;
    float o2 = y2 * c2 + y1 * s2;
    unsigned short h, l;
    split2(o1, h, l);
    kh[(size_t)row * DH + lane] = h;
    kl[(size_t)row * DH + lane] = l;
    split2(o2, h, l);
    kh[(size_t)row * DH + lane + 64] = h;
    kl[(size_t)row * DH + lane + 64] = l;
  } else {
    vh[(size_t)row * DH + lane] = f2bf(y1);
    vh[(size_t)row * DH + lane + 64] = f2bf(y2);
  }
}

// ---------------- Flash attention: QBLK=96, 6 waves; fused Q rms+rope; setprio ----------------
template <int WRITE_LO>
__global__ __launch_bounds__(384) void attn3(const float* __restrict__ Qf,
                                             const float* __restrict__ qnw,
                                             const float* __restrict__ cosp,
                                             const float* __restrict__ sinp,
                                             const unsigned short* __restrict__ Kh,
                                             const unsigned short* __restrict__ Kl,
                                             const unsigned short* __restrict__ Vth,
                                             unsigned short* __restrict__ Oh,
                                             unsigned short* __restrict__ Ol,
                                             const int* __restrict__ cu, int ncu) {
  __shared__ unsigned short kh_lds[32][136];
  __shared__ unsigned short kl_lds[32][136];
  __shared__ unsigned short vh_lds[144][40];
  __shared__ unsigned short ph_lds[6][16][40];

  int id = blockIdx.y * gridDim.x + blockIdx.x;
  int nid = (id & 7) * 64 + (id >> 3);
  const int qt = nid & 31, h = nid >> 5;
  const int qbase = qt * 96;
  const int kvh = h >> 1;
  const int tid = threadIdx.x, lane = tid & 63, wave = tid >> 6;
  const int g = lane >> 4, r16 = lane & 15;

  for (int i = tid; i < 16 * 40; i += 384) {
    int rr = i / 40, cc = i % 40;
    vh_lds[128 + rr][cc] = (rr == 0) ? (unsigned short)0x3F80 : (unsigned short)0;
  }

  bf16x8 aqh[4], aql[4];
  {
    int q_r = qbase + wave * 16 + r16;
    const float* xq = Qf + (size_t)q_r * HIDDEN + h * DH;
    float xv[4][8];
    float ss = 0.f;
#pragma unroll
    for (int ks = 0; ks < 4; ++ks) {
      f32x4 a = *(const f32x4*)(xq + ks * 32 + g * 8);
      f32x4 b = *(const f32x4*)(xq + ks * 32 + g * 8 + 4);
#pragma unroll
      for (int j = 0; j < 4; ++j) { xv[ks][j] = a[j]; xv[ks][4 + j] = b[j]; }
#pragma unroll
      for (int j = 0; j < 8; ++j) ss += xv[ks][j] * xv[ks][j];
    }
    ss += __shfl_xor(ss, 16, 64);
    ss += __shfl_xor(ss, 32, 64);
    float inv = rsqrtf(ss * (1.0f / 128.0f) + 1e-6f);
    float y[4][8];
#pragma unroll
    for (int ks = 0; ks < 4; ++ks) {
      f32x4 w0 = *(const f32x4*)(qnw + ks * 32 + g * 8);
      f32x4 w1 = *(const f32x4*)(qnw + ks * 32 + g * 8 + 4);
#pragma unroll
      for (int j = 0; j < 4; ++j) {
        y[ks][j] = xv[ks][j] * inv * w0[j];
        y[ks][4 + j] = xv[ks][4 + j] * inv * w1[j];
      }
    }
    const float* cb = cosp + (size_t)q_r * DH;
    const float* sb = sinp + (size_t)q_r * DH;
#pragma unroll
    for (int ks = 0; ks < 4; ++ks) {
      bf16x8 th, tl;
#pragma unroll
      for (int j2 = 0; j2 < 2; ++j2) {
        int col = ks * 32 + g * 8 + j2 * 4;
        f32x4 cv = *(const f32x4*)(cb + col);
        f32x4 sv = *(const f32x4*)(sb + col);
#pragma unroll
        for (int j = 0; j < 4; ++j) {
          float o;
          if (ks < 2) o = y[ks][j2 * 4 + j] * cv[j] - y[ks + 2][j2 * 4 + j] * sv[j];
          else        o = y[ks][j2 * 4 + j] * cv[j] + y[ks - 2][j2 * 4 + j] * sv[j];
          unsigned short hx, lx;
          split2(o, hx, lx);
          th[j2 * 4 + j] = (short)hx;
          tl[j2 * 4 + j] = (short)lx;
        }
      }
      aqh[ks] = th; aql[ks] = tl;
    }
  }

  int ssr[4];
#pragma unroll
  for (int r = 0; r < 4; ++r) {
    int q_r = qbase + wave * 16 + g * 4 + r;
    int s = 0;
    for (int i = 1; i < ncu; ++i) { int v = cu[i]; if (v <= q_r) s = v; }
    ssr[r] = s;
  }
  int ss_base = 0;
  for (int i = 1; i < ncu; ++i) { int v = cu[i]; if (v <= qbase) ss_base = v; }

  float m_r[4] = {-1e30f, -1e30f, -1e30f, -1e30f};
  f32x4 oacc[8];
#pragma unroll
  for (int db = 0; db < 8; ++db) oacc[db] = (f32x4){0.f, 0.f, 0.f, 0.f};
  f32x4 oaccL = (f32x4){0.f, 0.f, 0.f, 0.f};

  int lo = qbase - WINDOW + 1;
  if (lo < ss_base) lo = ss_base;
  if (lo < 0) lo = 0;
  int kt0 = lo & ~31;
  int ktend = qbase + 95;

  const bool stager = tid < 256;
  const int krow = (tid & 255) >> 3, kc = tid & 7;
  const int vd = (tid & 255) >> 1, vhalf = (tid & 1) * 16;
  const int qmin = qbase + wave * 16;
  const int sw0 = ((kc + 2 * (krow & 15)) & 15) * 16;
  const int sw1 = ((kc + 8 + 2 * (krow & 15)) & 15) * 16;

  ushort8 rkh0, rkh1, rkl0, rkl1, rvh0, rvh1;
  auto loadTile = [&](int kt) {
    if (!stager) return;
    size_t goff = ((size_t)(kt + krow) * NHKV + kvh) * DH + kc * 8;
    rkh0 = *(const ushort8*)(Kh + goff);
    rkh1 = *(const ushort8*)(Kh + goff + 64);
    rkl0 = *(const ushort8*)(Kl + goff);
    rkl1 = *(const ushort8*)(Kl + goff + 64);
    size_t voff = ((size_t)kvh * DH + vd) * T_TOK + kt + vhalf;
    rvh0 = *(const ushort8*)(Vth + voff);
    rvh1 = *(const ushort8*)(Vth + voff + 8);
  };
  auto writeTile = [&]() {
    if (!stager) return;
    char* kbh = (char*)&kh_lds[krow][0];
    char* kbl = (char*)&kl_lds[krow][0];
    *(ushort8*)(kbh + sw0) = rkh0;
    *(ushort8*)(kbh + sw1) = rkh1;
    *(ushort8*)(kbl + sw0) = rkl0;
    *(ushort8*)(kbl + sw1) = rkl1;
    *(ushort8*)&vh_lds[vd][vhalf] = rvh0;
    *(ushort8*)&vh_lds[vd][vhalf + 8] = rvh1;
  };

  loadTile(kt0);
  writeTile();
  __syncthreads();

  for (int kt = kt0; kt <= ktend; kt += 32) {
    const bool hasNext = (kt + 32 <= ktend);
    if (hasNext) loadTile(kt + 32);

    f32x4 s0 = (f32x4){0.f, 0.f, 0.f, 0.f}, s1 = (f32x4){0.f, 0.f, 0.f, 0.f};
    {
      const char* kb0h = (const char*)&kh_lds[r16][0];
      const char* kb1h = (const char*)&kh_lds[16 + r16][0];
      const char* kb0l = (const char*)&kl_lds[r16][0];
      const char* kb1l = (const char*)&kl_lds[16 + r16][0];
      __builtin_amdgcn_s_setprio(1);
#pragma unroll
      for (int ks = 0; ks < 4; ++ks) {
        int sl = ((ks * 4 + g + 2 * r16) & 15) * 16;
        bf16x8 bh0 = *(const bf16x8*)(kb0h + sl);
        bf16x8 bh1 = *(const bf16x8*)(kb1h + sl);
        bf16x8 bl0 = *(const bf16x8*)(kb0l + sl);
        bf16x8 bl1 = *(const bf16x8*)(kb1l + sl);
        s0 = __builtin_amdgcn_mfma_f32_16x16x32_bf16(aqh[ks], bh0, s0, 0, 0, 0);
        s0 = __builtin_amdgcn_mfma_f32_16x16x32_bf16(aqh[ks], bl0, s0, 0, 0, 0);
        s0 = __builtin_amdgcn_mfma_f32_16x16x32_bf16(aql[ks], bh0, s0, 0, 0, 0);
        s1 = __builtin_amdgcn_mfma_f32_16x16x32_bf16(aqh[ks], bh1, s1, 0, 0, 0);
        s1 = __builtin_amdgcn_mfma_f32_16x16x32_bf16(aqh[ks], bl1, s1, 0, 0, 0);
        s1 = __builtin_amdgcn_mfma_f32_16x16x32_bf16(aql[ks], bh1, s1, 0, 0, 0);
      }
      __builtin_amdgcn_s_setprio(0);
    }

    float sv0_[4], sv1_[4], mt_[4];
    bool ok0_[4], ok1_[4];
    bool interior = (kt + 31 <= qmin) && (kt >= qmin + 16 - WINDOW) &&
                    __all(kt >= ssr[3]);
    if (interior) {
#pragma unroll
      for (int r = 0; r < 4; ++r) {
        ok0_[r] = ok1_[r] = true;
        sv0_[r] = s0[r]; sv1_[r] = s1[r];
      }
    } else {
#pragma unroll
      for (int r = 0; r < 4; ++r) {
        int q_r = qmin + g * 4 + r;
        int k0 = kt + r16, k1 = k0 + 16;
        ok0_[r] = (k0 <= q_r) && (k0 > q_r - WINDOW) && (k0 >= ssr[r]);
        ok1_[r] = (k1 <= q_r) && (k1 > q_r - WINDOW) && (k1 >= ssr[r]);
        sv0_[r] = ok0_[r] ? s0[r] : -1e30f;
        sv1_[r] = ok1_[r] ? s1[r] : -1e30f;
      }
    }
#pragma unroll
    for (int r = 0; r < 4; ++r) {
      float mt = fmaxf(sv0_[r], sv1_[r]);
#pragma unroll
      for (int mm = 1; mm < 16; mm <<= 1) mt = fmaxf(mt, __shfl_xor(mt, mm, 64));
      mt_[r] = mt;
    }
    float grow = fmaxf(fmaxf(mt_[0] - m_r[0], mt_[1] - m_r[1]),
                       fmaxf(mt_[2] - m_r[2], mt_[3] - m_r[3]));
    if (!__all(grow <= 8.0f)) {
#pragma unroll
      for (int r = 0; r < 4; ++r) {
        float mnew = fmaxf(m_r[r], mt_[r]);
        float alpha = __expf(m_r[r] - mnew);
        m_r[r] = mnew;
#pragma unroll
        for (int db = 0; db < 8; ++db) oacc[db][r] *= alpha;
        oaccL[r] *= alpha;
      }
    }
#pragma unroll
    for (int r = 0; r < 4; ++r) {
      float p0v = ok0_[r] ? __expf(sv0_[r] - m_r[r]) : 0.f;
      float p1v = ok1_[r] ? __expf(sv1_[r] - m_r[r]) : 0.f;
      ph_lds[wave][g * 4 + r][r16] = f2bf(p0v);
      ph_lds[wave][g * 4 + r][16 + r16] = f2bf(p1v);
    }

    bf16x8 pah = *(const bf16x8*)&ph_lds[wave][r16][g * 8];
    __builtin_amdgcn_s_setprio(1);
#pragma unroll
    for (int db = 0; db < 8; ++db) {
      bf16x8 vfh = *(const bf16x8*)&vh_lds[db * 16 + r16][g * 8];
      oacc[db] = __builtin_amdgcn_mfma_f32_16x16x32_bf16(pah, vfh, oacc[db], 0, 0, 0);
    }
    {
      bf16x8 vfo = *(const bf16x8*)&vh_lds[128 + r16][g * 8];
      oaccL = __builtin_amdgcn_mfma_f32_16x16x32_bf16(pah, vfo, oaccL, 0, 0, 0);
    }
    __builtin_amdgcn_s_setprio(0);

    __syncthreads();
    if (hasNext) writeTile();
    __syncthreads();
  }

#pragma unroll
  for (int r = 0; r < 4; ++r) {
    int q_r = qbase + wave * 16 + g * 4 + r;
    float lsum = __shfl(oaccL[r], lane & 48, 64);
    float invl = 1.f / lsum;
#pragma unroll
    for (int db = 0; db < 8; ++db) {
      float ov = oacc[db][r] * invl;
      unsigned short hh, ll;
      split2(ov, hh, ll);
      Oh[(size_t)q_r * (NHQ * DH) + h * DH + db * 16 + r16] = hh;
      if (WRITE_LO) Ol[(size_t)q_r * (NHQ * DH) + h * DH + db * 16 + r16] = ll;
    }
  }
}

extern "C" void kernel_launch(void* const* d_in, const int* in_sizes, int n_in,
                              void* d_out, int out_size, void* d_ws, size_t ws_size,
                              hipStream_t stream) {
  const float* hidden = (const float*)d_in[0];
  const float* cosp   = (const float*)d_in[1];
  const float* sinp   = (const float*)d_in[2];
  const float* wq0    = (const float*)d_in[3];
  const float* wk0    = (const float*)d_in[4];
  const float* wv0    = (const float*)d_in[5];
  const float* wo0    = (const float*)d_in[6];
  const float* qn0    = (const float*)d_in[7];
  const float* kn0    = (const float*)d_in[8];
  const float* wq1    = (const float*)d_in[9];
  const float* wo1    = (const float*)d_in[10];
  const float* qn1    = (const float*)d_in[11];
  const int*   cu     = (const int*)d_in[12];
  int ncu = in_sizes[12];
  (void)n_in; (void)out_size; (void)ws_size;

  char* p = (char*)d_ws;
  auto alloc = [&](size_t bytes) { char* r = p; p += (bytes + 255) & ~255ull; return r; };

  unsigned short* wqkvh = (unsigned short*)alloc((size_t)2 * HIDDEN * HIDDEN * 2);
  unsigned short* wqkvl = (unsigned short*)alloc((size_t)2 * HIDDEN * HIDDEN * 2);
  unsigned short* wo0sh = (unsigned short*)alloc((size_t)HIDDEN * HIDDEN * 2);
  unsigned short* wo0sl = (unsigned short*)alloc((size_t)HIDDEN * HIDDEN * 2);
  unsigned short* wq1th = (unsigned short*)alloc((size_t)HIDDEN * HIDDEN * 2);
  unsigned short* wq1tl = (unsigned short*)alloc((size_t)HIDDEN * HIDDEN * 2);
  unsigned short* wo1t  = (unsigned short*)alloc((size_t)HIDDEN * HIDDEN * 2);
  float*          c32q  = (float*)alloc((size_t)T_TOK * HIDDEN * 4);  // Q fp32 -> later W01 hi/lo
  float*          c32kv = (float*)alloc((size_t)T_TOK * HIDDEN * 4);  // KV fp32 -> later q1_pre fp32
  unsigned short* xh    = (unsigned short*)alloc((size_t)T_TOK * HIDDEN * 2);
  unsigned short* xl    = (unsigned short*)alloc((size_t)T_TOK * HIDDEN * 2);
  unsigned short* kh    = (unsigned short*)alloc((size_t)T_TOK * KVN * 2);
  unsigned short* kl    = (unsigned short*)alloc((size_t)T_TOK * KVN * 2);
  unsigned short* vh    = (unsigned short*)alloc((size_t)T_TOK * KVN * 2);
  unsigned short* vth   = (unsigned short*)alloc((size_t)T_TOK * KVN * 2);

  unsigned short* W01th = (unsigned short*)c32q;
  unsigned short* W01tl = W01th + (size_t)HIDDEN * HIDDEN;

  // 1. all independent preprocessing in ONE launch (incl. wo1 transpose)
  prep<<<26624, 256, 0, stream>>>(hidden, wq0, wk0, wv0, wo0, wq1, wo1,
                                  xh, xl, wqkvh, wqkvl, wo0sh, wo0sl, wq1th, wq1tl, wo1t);

  // 2. mega-fused QKV projection; V-blocks 1-term, XCD-balanced bn interleave
  gemm3_qkv<<<dim3(T_TOK / 128, 4096 / 128), 256, 0, stream>>>(
      xh, xl, wqkvh, wqkvl, c32q, c32kv, HIDDEN, T_TOK, 4096, HIDDEN);

  // 3. K/V norms + V transpose
  rms_kv<<<2 * T_TOK * NHKV / 4, 256, 0, stream>>>(c32kv, kn0, cosp, sinp, kh, kl, vh);
  transpose_u16<<<dim3(KVN / 32, T_TOK / 32), 256, 0, stream>>>(vh, vth, T_TOK, KVN);

  // 4. attn0 (fused Q-rms from c32q) -> o0 in xh/xl
  attn3<1><<<dim3(32, 16), 384, 0, stream>>>(c32q, qn0, cosp, sinp, kh, kl, vth, xh, xl, cu, ncu);

  // 5. W01t = wq1^T · wo0^T (512 blocks = 2/CU); into c32q region (Q dead)
  gemm3_64<<<dim3(HIDDEN / 64, HIDDEN / 128), 256, 0, stream>>>(
      wq1th, wq1tl, wo0sh, wo0sl, W01th, W01tl, HIDDEN, HIDDEN, HIDDEN);

  // 6. q1_pre = o0 @ W01 -> c32kv (KV fp32 dead)
  gemm3_96<<<dim3(T_TOK / 96, HIDDEN / 128), 256, 0, stream>>>(
      xh, xl, W01th, W01tl, c32kv, T_TOK, HIDDEN, HIDDEN);

  // 7. attn1 -> xh (hi only)
  attn3<0><<<dim3(32, 16), 384, 0, stream>>>(c32kv, qn1, cosp, sinp, kh, kl, vth, xh, nullptr, cu, ncu);

  // 8. final projection (1-term, linear path)
  gemm1_96<<<dim3(T_TOK / 96, HIDDEN / 128), 256, 0, stream>>>(xh, wo1t, (float*)d_out, T_TOK, HIDDEN, HIDDEN);
}

// Round 17
// 657.956 us; speedup vs baseline: 1.0357x; 1.0357x over previous
//
#include <hip/hip_runtime.h>
#include <hip/hip_bf16.h>

#define T_TOK 3072
#define HIDDEN 2048
#define NHQ 16
#define NHKV 8
#define DH 128
#define WINDOW 1024
#define KVN 1024

typedef __attribute__((ext_vector_type(4))) float f32x4;
typedef __attribute__((ext_vector_type(8))) short bf16x8;
typedef __attribute__((ext_vector_type(8))) unsigned short ushort8;
typedef __attribute__((ext_vector_type(4))) unsigned short ushort4v;

__device__ __forceinline__ unsigned short f2bf(float f) {
  union { float fv; unsigned u; } v; v.fv = f;
  unsigned r = v.u + 0x7fffu + ((v.u >> 16) & 1u);
  return (unsigned short)(r >> 16);
}
__device__ __forceinline__ float bf2f(unsigned short h) {
  union { unsigned u; float f; } v; v.u = ((unsigned)h) << 16;
  return v.f;
}
__device__ __forceinline__ void split2(float f, unsigned short& hi, unsigned short& lo) {
  hi = f2bf(f);
  lo = f2bf(f - bf2f(hi));
}

// ---------------- mega-prep: ALL independent input preprocessing in ONE launch ----------------
__global__ __launch_bounds__(256) void prep(const float* __restrict__ hidden,
                                            const float* __restrict__ wq0,
                                            const float* __restrict__ wk0,
                                            const float* __restrict__ wv0,
                                            const float* __restrict__ wo0,
                                            const float* __restrict__ wq1,
                                            const float* __restrict__ wo1,
                                            unsigned short* __restrict__ xh,
                                            unsigned short* __restrict__ xl,
                                            unsigned short* __restrict__ wqkvh,
                                            unsigned short* __restrict__ wqkvl,
                                            unsigned short* __restrict__ wo0sh,
                                            unsigned short* __restrict__ wo0sl,
                                            unsigned short* __restrict__ wq1th,
                                            unsigned short* __restrict__ wq1tl,
                                            unsigned short* __restrict__ wo1th) {
  __shared__ float tile[32][33];
  const int K = HIDDEN;
  int id = blockIdx.x;
  if (id < 6144 || (id >= 14336 && id < 18432)) {
    const float* src; unsigned short *dh, *dl; int local;
    if (id < 6144) { src = hidden; dh = xh; dl = xl; local = id; }
    else           { src = wo0; dh = wo0sh; dl = wo0sl; local = id - 14336; }
    int i = (local * 256 + threadIdx.x) * 4;
    f32x4 v = *(const f32x4*)(src + i);
    ushort4v oh, ol;
#pragma unroll
    for (int j = 0; j < 4; ++j) {
      unsigned short h, l;
      split2(v[j], h, l);
      oh[j] = h; ol[j] = l;
    }
    *(ushort4v*)(dh + i) = oh;
    *(ushort4v*)(dl + i) = ol;
    return;
  }
  const float* W; int N, local; unsigned short *Dh, *Dl; size_t dstoff;
  if (id < 14336) {
    int lid = id - 6144;
    if (lid < 4096)      { W = wq0; N = 2048; local = lid;        dstoff = 0; }
    else if (lid < 6144) { W = wk0; N = 1024; local = lid - 4096; dstoff = (size_t)2048 * K; }
    else                 { W = wv0; N = 1024; local = lid - 6144; dstoff = (size_t)3072 * K; }
    Dh = wqkvh; Dl = wqkvl;
  } else if (id < 22528) {
    W = wq1; N = 2048; local = id - 18432; dstoff = 0;
    Dh = wq1th; Dl = wq1tl;
  } else {
    W = wo1; N = 2048; local = id - 22528; dstoff = 0;
    Dh = wo1th; Dl = nullptr;
  }
  int ntc = N / 32;
  int bn = (local % ntc) * 32, bk = (local / ntc) * 32;
  int tx = threadIdx.x & 31, ty = threadIdx.x >> 5;
#pragma unroll
  for (int i = 0; i < 4; ++i)
    tile[ty + i * 8][tx] = W[(size_t)(bk + ty + i * 8) * N + bn + tx];
  __syncthreads();
#pragma unroll
  for (int i = 0; i < 4; ++i) {
    unsigned short h, l;
    split2(tile[tx][ty + i * 8], h, l);
    Dh[dstoff + (size_t)(bn + ty + i * 8) * K + bk + tx] = h;
    if (Dl) Dl[dstoff + (size_t)(bn + ty + i * 8) * K + bk + tx] = l;
  }
}

// ---------------- generic u16 transpose ----------------
__global__ __launch_bounds__(256) void transpose_u16(const unsigned short* __restrict__ src,
                                                     unsigned short* __restrict__ dst,
                                                     int R, int C) {
  __shared__ unsigned short tile[32][33];
  int bc = blockIdx.x * 32, br = blockIdx.y * 32;
  int tx = threadIdx.x & 31, ty = threadIdx.x >> 5;
#pragma unroll
  for (int i = 0; i < 4; ++i)
    tile[ty + i * 8][tx] = src[(size_t)(br + ty + i * 8) * C + bc + tx];
  __syncthreads();
#pragma unroll
  for (int i = 0; i < 4; ++i)
    dst[(size_t)(bc + ty + i * 8) * R + br + tx] = tile[tx][ty + i * 8];
}

#define GSLOT(lane) ((((lane) & 3) + 4 - (((lane) >> 3) & 3)) & 3)

// ---------------- 3-term split GEMM, 128x128 tile (dual fp32 out) — r15 proven ----------------
__global__ __launch_bounds__(256) void gemm3_128(const unsigned short* __restrict__ Ah,
                                                 const unsigned short* __restrict__ Al,
                                                 const unsigned short* __restrict__ Bh,
                                                 const unsigned short* __restrict__ Bl,
                                                 float* __restrict__ Cq,
                                                 float* __restrict__ Ckv,
                                                 int strd, int M, int N, int K) {
  __shared__ unsigned short ah_lds[128 * 32];
  __shared__ unsigned short al_lds[128 * 32];
  __shared__ unsigned short bh_lds[128 * 32];
  __shared__ unsigned short bl_lds[128 * 32];
  const int tid = threadIdx.x, lane = tid & 63, wave = tid >> 6;
  const int wr = (wave >> 1) * 64, wc = (wave & 1) * 64;
  const int g = lane >> 4, r16 = lane & 15;
  int nwg = gridDim.x * gridDim.y;
  int id = blockIdx.y * gridDim.x + blockIdx.x;
  int nid = (id & 7) * (nwg >> 3) + (id >> 3);
  const int bm = nid % gridDim.x, bn = nid / gridDim.x;
  f32x4 acc[4][4];
#pragma unroll
  for (int i = 0; i < 4; ++i)
#pragma unroll
    for (int j = 0; j < 4; ++j) acc[i][j] = (f32x4){0.f, 0.f, 0.f, 0.f};

  const unsigned short* AhB = Ah + (size_t)bm * 128 * K;
  const unsigned short* AlB = Al + (size_t)bm * 128 * K;
  const unsigned short* BhB = Bh + (size_t)bn * 128 * K;
  const unsigned short* BlB = Bl + (size_t)bn * 128 * K;

  const int slg = GSLOT(lane) * 8;
  const int sr = ((r16 >> 1) & 3);

  for (int kt = 0; kt < K; kt += 32) {
    __syncthreads();
#pragma unroll
    for (int c = 0; c < 2; ++c) {
      size_t goff = (size_t)(wave * 32 + c * 16 + (lane >> 2)) * K + kt + slg;
      int loff = (wave * 2 + c) * 512;
      __builtin_amdgcn_global_load_lds(
          (const __attribute__((address_space(1))) unsigned int*)(AhB + goff),
          (__attribute__((address_space(3))) unsigned int*)(ah_lds + loff), 16, 0, 0);
      __builtin_amdgcn_global_load_lds(
          (const __attribute__((address_space(1))) unsigned int*)(AlB + goff),
          (__attribute__((address_space(3))) unsigned int*)(al_lds + loff), 16, 0, 0);
      __builtin_amdgcn_global_load_lds(
          (const __attribute__((address_space(1))) unsigned int*)(BhB + goff),
          (__attribute__((address_space(3))) unsigned int*)(bh_lds + loff), 16, 0, 0);
      __builtin_amdgcn_global_load_lds(
          (const __attribute__((address_space(1))) unsigned int*)(BlB + goff),
          (__attribute__((address_space(3))) unsigned int*)(bl_lds + loff), 16, 0, 0);
    }
    __syncthreads();
    bf16x8 ahf[4], alf[4], bhf[4], blf[4];
    int sa = ((g + sr) & 3) * 8;
#pragma unroll
    for (int i = 0; i < 4; ++i) {
      ahf[i] = *(const bf16x8*)&ah_lds[(wr + i * 16 + r16) * 32 + sa];
      alf[i] = *(const bf16x8*)&al_lds[(wr + i * 16 + r16) * 32 + sa];
      bhf[i] = *(const bf16x8*)&bh_lds[(wc + i * 16 + r16) * 32 + sa];
      blf[i] = *(const bf16x8*)&bl_lds[(wc + i * 16 + r16) * 32 + sa];
    }
#pragma unroll
    for (int i = 0; i < 4; ++i)
#pragma unroll
      for (int j = 0; j < 4; ++j) {
        acc[i][j] = __builtin_amdgcn_mfma_f32_16x16x32_bf16(ahf[i], bhf[j], acc[i][j], 0, 0, 0);
        acc[i][j] = __builtin_amdgcn_mfma_f32_16x16x32_bf16(ahf[i], blf[j], acc[i][j], 0, 0, 0);
        acc[i][j] = __builtin_amdgcn_mfma_f32_16x16x32_bf16(alf[i], bhf[j], acc[i][j], 0, 0, 0);
      }
  }

#pragma unroll
  for (int i = 0; i < 4; ++i) {
    int row = bm * 128 + wr + i * 16 + g * 4;
#pragma unroll
    for (int j = 0; j < 4; ++j) {
      int colg = bn * 128 + wc + j * 16 + r16;
      float* Cb; int cc;
      if (colg < 2048) { Cb = Cq; cc = colg; } else { Cb = Ckv; cc = colg - 2048; }
#pragma unroll
      for (int r = 0; r < 4; ++r)
        Cb[(size_t)(row + r) * strd + cc] = acc[i][j][r];
    }
  }
}

// ---------------- 3-term split GEMM, 64x128 tile, hi/lo bf16 out (W01) ----------------
__global__ __launch_bounds__(256) void gemm3_64(const unsigned short* __restrict__ Ah,
                                                const unsigned short* __restrict__ Al,
                                                const unsigned short* __restrict__ Bh,
                                                const unsigned short* __restrict__ Bl,
                                                unsigned short* __restrict__ Ch,
                                                unsigned short* __restrict__ Cl,
                                                int M, int N, int K) {
  __shared__ unsigned short ah_lds[64 * 32];
  __shared__ unsigned short al_lds[64 * 32];
  __shared__ unsigned short bh_lds[128 * 32];
  __shared__ unsigned short bl_lds[128 * 32];
  const int tid = threadIdx.x, lane = tid & 63, wave = tid >> 6;
  const int wr = (wave >> 1) * 32, wc = (wave & 1) * 64;
  const int g = lane >> 4, r16 = lane & 15;
  int nwg = gridDim.x * gridDim.y;
  int id = blockIdx.y * gridDim.x + blockIdx.x;
  int nid = (id & 7) * (nwg >> 3) + (id >> 3);
  const int bm = nid % gridDim.x, bn = nid / gridDim.x;
  f32x4 acc[2][4];
#pragma unroll
  for (int i = 0; i < 2; ++i)
#pragma unroll
    for (int j = 0; j < 4; ++j) acc[i][j] = (f32x4){0.f, 0.f, 0.f, 0.f};

  const unsigned short* AhB = Ah + (size_t)bm * 64 * K;
  const unsigned short* AlB = Al + (size_t)bm * 64 * K;
  const unsigned short* BhB = Bh + (size_t)bn * 128 * K;
  const unsigned short* BlB = Bl + (size_t)bn * 128 * K;

  const int slg = GSLOT(lane) * 8;
  const int sr = ((r16 >> 1) & 3);

  for (int kt = 0; kt < K; kt += 32) {
    __syncthreads();
    {
      size_t goff = (size_t)(wave * 16 + (lane >> 2)) * K + kt + slg;
      __builtin_amdgcn_global_load_lds(
          (const __attribute__((address_space(1))) unsigned int*)(AhB + goff),
          (__attribute__((address_space(3))) unsigned int*)(ah_lds + wave * 512), 16, 0, 0);
      __builtin_amdgcn_global_load_lds(
          (const __attribute__((address_space(1))) unsigned int*)(AlB + goff),
          (__attribute__((address_space(3))) unsigned int*)(al_lds + wave * 512), 16, 0, 0);
    }
#pragma unroll
    for (int c = 0; c < 2; ++c) {
      size_t goff = (size_t)(wave * 32 + c * 16 + (lane >> 2)) * K + kt + slg;
      int loff = (wave * 2 + c) * 512;
      __builtin_amdgcn_global_load_lds(
          (const __attribute__((address_space(1))) unsigned int*)(BhB + goff),
          (__attribute__((address_space(3))) unsigned int*)(bh_lds + loff), 16, 0, 0);
      __builtin_amdgcn_global_load_lds(
          (const __attribute__((address_space(1))) unsigned int*)(BlB + goff),
          (__attribute__((address_space(3))) unsigned int*)(bl_lds + loff), 16, 0, 0);
    }
    __syncthreads();
    bf16x8 ahf[2], alf[2], bhf[4], blf[4];
    int sa = ((g + sr) & 3) * 8;
#pragma unroll
    for (int i = 0; i < 2; ++i) {
      ahf[i] = *(const bf16x8*)&ah_lds[(wr + i * 16 + r16) * 32 + sa];
      alf[i] = *(const bf16x8*)&al_lds[(wr + i * 16 + r16) * 32 + sa];
    }
#pragma unroll
    for (int j = 0; j < 4; ++j) {
      bhf[j] = *(const bf16x8*)&bh_lds[(wc + j * 16 + r16) * 32 + sa];
      blf[j] = *(const bf16x8*)&bl_lds[(wc + j * 16 + r16) * 32 + sa];
    }
#pragma unroll
    for (int i = 0; i < 2; ++i)
#pragma unroll
      for (int j = 0; j < 4; ++j) {
        acc[i][j] = __builtin_amdgcn_mfma_f32_16x16x32_bf16(ahf[i], bhf[j], acc[i][j], 0, 0, 0);
        acc[i][j] = __builtin_amdgcn_mfma_f32_16x16x32_bf16(ahf[i], blf[j], acc[i][j], 0, 0, 0);
        acc[i][j] = __builtin_amdgcn_mfma_f32_16x16x32_bf16(alf[i], bhf[j], acc[i][j], 0, 0, 0);
      }
  }

#pragma unroll
  for (int i = 0; i < 2; ++i) {
    int row = bm * 64 + wr + i * 16 + g * 4;
#pragma unroll
    for (int j = 0; j < 4; ++j) {
      int col = bn * 128 + wc + j * 16 + r16;
#pragma unroll
      for (int r = 0; r < 4; ++r) {
        unsigned short h, l;
        split2(acc[i][j][r], h, l);
        Ch[(size_t)(row + r) * N + col] = h;
        Cl[(size_t)(row + r) * N + col] = l;
      }
    }
  }
}

// ---------------- 3-term split GEMM, 96x128 tile (fp32 out) ----------------
__global__ __launch_bounds__(256) void gemm3_96(const unsigned short* __restrict__ Ah,
                                                const unsigned short* __restrict__ Al,
                                                const unsigned short* __restrict__ Bh,
                                                const unsigned short* __restrict__ Bl,
                                                float* __restrict__ Cf,
                                                int M, int N, int K) {
  __shared__ unsigned short ah_lds[96 * 32];
  __shared__ unsigned short al_lds[96 * 32];
  __shared__ unsigned short bh_lds[128 * 32];
  __shared__ unsigned short bl_lds[128 * 32];
  const int tid = threadIdx.x, lane = tid & 63, wave = tid >> 6;
  const int wr = (wave >> 1) * 48, wc = (wave & 1) * 64;
  const int g = lane >> 4, r16 = lane & 15;
  int nwg = gridDim.x * gridDim.y;
  int id = blockIdx.y * gridDim.x + blockIdx.x;
  int nid = (id & 7) * (nwg >> 3) + (id >> 3);
  const int bm = nid % gridDim.x, bn = nid / gridDim.x;
  f32x4 acc[3][4];
#pragma unroll
  for (int i = 0; i < 3; ++i)
#pragma unroll
    for (int j = 0; j < 4; ++j) acc[i][j] = (f32x4){0.f, 0.f, 0.f, 0.f};

  const unsigned short* AhB = Ah + (size_t)bm * 96 * K;
  const unsigned short* AlB = Al + (size_t)bm * 96 * K;
  const unsigned short* BhB = Bh + (size_t)bn * 128 * K;
  const unsigned short* BlB = Bl + (size_t)bn * 128 * K;

  const int slg = GSLOT(lane) * 8;
  const int sr = ((r16 >> 1) & 3);

  for (int kt = 0; kt < K; kt += 32) {
    __syncthreads();
    {
      int c = wave;
      size_t goff = (size_t)(c * 16 + (lane >> 2)) * K + kt + slg;
      __builtin_amdgcn_global_load_lds(
          (const __attribute__((address_space(1))) unsigned int*)(AhB + goff),
          (__attribute__((address_space(3))) unsigned int*)(ah_lds + c * 512), 16, 0, 0);
      __builtin_amdgcn_global_load_lds(
          (const __attribute__((address_space(1))) unsigned int*)(AlB + goff),
          (__attribute__((address_space(3))) unsigned int*)(al_lds + c * 512), 16, 0, 0);
      if (wave < 2) {
        int c2 = 4 + wave;
        size_t goff2 = (size_t)(c2 * 16 + (lane >> 2)) * K + kt + slg;
        __builtin_amdgcn_global_load_lds(
            (const __attribute__((address_space(1))) unsigned int*)(AhB + goff2),
            (__attribute__((address_space(3))) unsigned int*)(ah_lds + c2 * 512), 16, 0, 0);
        __builtin_amdgcn_global_load_lds(
            (const __attribute__((address_space(1))) unsigned int*)(AlB + goff2),
            (__attribute__((address_space(3))) unsigned int*)(al_lds + c2 * 512), 16, 0, 0);
      }
    }
#pragma unroll
    for (int c = 0; c < 2; ++c) {
      size_t goff = (size_t)(wave * 32 + c * 16 + (lane >> 2)) * K + kt + slg;
      int loff = (wave * 2 + c) * 512;
      __builtin_amdgcn_global_load_lds(
          (const __attribute__((address_space(1))) unsigned int*)(BhB + goff),
          (__attribute__((address_space(3))) unsigned int*)(bh_lds + loff), 16, 0, 0);
      __builtin_amdgcn_global_load_lds(
          (const __attribute__((address_space(1))) unsigned int*)(BlB + goff),
          (__attribute__((address_space(3))) unsigned int*)(bl_lds + loff), 16, 0, 0);
    }
    __syncthreads();
    bf16x8 ahf[3], alf[3], bhf[4], blf[4];
    int sa = ((g + sr) & 3) * 8;
#pragma unroll
    for (int i = 0; i < 3; ++i) {
      ahf[i] = *(const bf16x8*)&ah_lds[(wr + i * 16 + r16) * 32 + sa];
      alf[i] = *(const bf16x8*)&al_lds[(wr + i * 16 + r16) * 32 + sa];
    }
#pragma unroll
    for (int j = 0; j < 4; ++j) {
      bhf[j] = *(const bf16x8*)&bh_lds[(wc + j * 16 + r16) * 32 + sa];
      blf[j] = *(const bf16x8*)&bl_lds[(wc + j * 16 + r16) * 32 + sa];
    }
#pragma unroll
    for (int i = 0; i < 3; ++i)
#pragma unroll
      for (int j = 0; j < 4; ++j) {
        acc[i][j] = __builtin_amdgcn_mfma_f32_16x16x32_bf16(ahf[i], bhf[j], acc[i][j], 0, 0, 0);
        acc[i][j] = __builtin_amdgcn_mfma_f32_16x16x32_bf16(ahf[i], blf[j], acc[i][j], 0, 0, 0);
        acc[i][j] = __builtin_amdgcn_mfma_f32_16x16x32_bf16(alf[i], bhf[j], acc[i][j], 0, 0, 0);
      }
  }

#pragma unroll
  for (int i = 0; i < 3; ++i) {
    int row = bm * 96 + wr + i * 16 + g * 4;
#pragma unroll
    for (int j = 0; j < 4; ++j) {
      int col = bn * 128 + wc + j * 16 + r16;
#pragma unroll
      for (int r = 0; r < 4; ++r)
        Cf[(size_t)(row + r) * N + col] = acc[i][j][r];
    }
  }
}

// ---------------- 1-term bf16 GEMM, 96x128 tile ----------------
__global__ __launch_bounds__(256) void gemm1_96(const unsigned short* __restrict__ Ah,
                                                const unsigned short* __restrict__ Bh,
                                                float* __restrict__ Cf,
                                                int M, int N, int K) {
  __shared__ unsigned short ah_lds[96 * 32];
  __shared__ unsigned short bh_lds[128 * 32];
  const int tid = threadIdx.x, lane = tid & 63, wave = tid >> 6;
  const int wr = (wave >> 1) * 48, wc = (wave & 1) * 64;
  const int g = lane >> 4, r16 = lane & 15;
  int nwg = gridDim.x * gridDim.y;
  int id = blockIdx.y * gridDim.x + blockIdx.x;
  int nid = (id & 7) * (nwg >> 3) + (id >> 3);
  const int bm = nid % gridDim.x, bn = nid / gridDim.x;
  f32x4 acc[3][4];
#pragma unroll
  for (int i = 0; i < 3; ++i)
#pragma unroll
    for (int j = 0; j < 4; ++j) acc[i][j] = (f32x4){0.f, 0.f, 0.f, 0.f};

  const unsigned short* AhB = Ah + (size_t)bm * 96 * K;
  const unsigned short* BhB = Bh + (size_t)bn * 128 * K;

  const int slg = GSLOT(lane) * 8;
  const int sr = ((r16 >> 1) & 3);

  for (int kt = 0; kt < K; kt += 32) {
    __syncthreads();
    {
      int c = wave;
      size_t goff = (size_t)(c * 16 + (lane >> 2)) * K + kt + slg;
      __builtin_amdgcn_global_load_lds(
          (const __attribute__((address_space(1))) unsigned int*)(AhB + goff),
          (__attribute__((address_space(3))) unsigned int*)(ah_lds + c * 512), 16, 0, 0);
      if (wave < 2) {
        int c2 = 4 + wave;
        size_t goff2 = (size_t)(c2 * 16 + (lane >> 2)) * K + kt + slg;
        __builtin_amdgcn_global_load_lds(
            (const __attribute__((address_space(1))) unsigned int*)(AhB + goff2),
            (__attribute__((address_space(3))) unsigned int*)(ah_lds + c2 * 512), 16, 0, 0);
      }
    }
#pragma unroll
    for (int c = 0; c < 2; ++c) {
      size_t goff = (size_t)(wave * 32 + c * 16 + (lane >> 2)) * K + kt + slg;
      __builtin_amdgcn_global_load_lds(
          (const __attribute__((address_space(1))) unsigned int*)(BhB + goff),
          (__attribute__((address_space(3))) unsigned int*)(bh_lds + (wave * 2 + c) * 512), 16, 0, 0);
    }
    __syncthreads();
    bf16x8 ahf[3], bhf[4];
    int sa = ((g + sr) & 3) * 8;
#pragma unroll
    for (int i = 0; i < 3; ++i)
      ahf[i] = *(const bf16x8*)&ah_lds[(wr + i * 16 + r16) * 32 + sa];
#pragma unroll
    for (int j = 0; j < 4; ++j)
      bhf[j] = *(const bf16x8*)&bh_lds[(wc + j * 16 + r16) * 32 + sa];
#pragma unroll
    for (int i = 0; i < 3; ++i)
#pragma unroll
      for (int j = 0; j < 4; ++j)
        acc[i][j] = __builtin_amdgcn_mfma_f32_16x16x32_bf16(ahf[i], bhf[j], acc[i][j], 0, 0, 0);
  }

#pragma unroll
  for (int i = 0; i < 3; ++i) {
    int row = bm * 96 + wr + i * 16 + g * 4;
#pragma unroll
    for (int j = 0; j < 4; ++j) {
      int col = bn * 128 + wc + j * 16 + r16;
#pragma unroll
      for (int r = 0; r < 4; ++r)
        Cf[(size_t)(row + r) * N + col] = acc[i][j][r];
    }
  }
}

// ---------------- merged K+V RMSNorm ----------------
__global__ __launch_bounds__(256) void rms_kv(const float* __restrict__ X,
                                              const float* __restrict__ kn,
                                              const float* __restrict__ cosp,
                                              const float* __restrict__ sinp,
                                              unsigned short* __restrict__ kh,
                                              unsigned short* __restrict__ kl,
                                              unsigned short* __restrict__ vh) {
  const int half = T_TOK * NHKV / 4;
  bool isV = (int)blockIdx.x >= half;
  int bid = isV ? blockIdx.x - half : blockIdx.x;
  int row = bid * 4 + (threadIdx.x >> 6);
  int lane = threadIdx.x & 63;
  int t = row >> 3, hh_ = row & 7;
  const float* x = X + (size_t)t * HIDDEN + (isV ? KVN : 0) + (size_t)hh_ * DH;
  float x1 = x[lane], x2 = x[lane + 64];
  float ss = x1 * x1 + x2 * x2;
#pragma unroll
  for (int m = 1; m < 64; m <<= 1) ss += __shfl_xor(ss, m, 64);
  float inv = rsqrtf(ss * (1.0f / 128.0f) + 1e-6f);
  float y1 = x1 * inv, y2 = x2 * inv;
  if (!isV) {
    y1 *= kn[lane]; y2 *= kn[lane + 64];
    float c1 = cosp[t * DH + lane], s1 = sinp[t * DH + lane];
    float c2 = cosp[t * DH + lane + 64], s2 = sinp[t * DH + lane + 64];
    float o1 = y1 * c1 - y2 * s1;
    float o2 = y2 * c2 + y1 * s2;
    unsigned short h, l;
    split2(o1, h, l);
    kh[(size_t)row * DH + lane] = h;
    kl[(size_t)row * DH + lane] = l;
    split2(o2, h, l);
    kh[(size_t)row * DH + lane + 64] = h;
    kl[(size_t)row * DH + lane + 64] = l;
  } else {
    vh[(size_t)row * DH + lane] = f2bf(y1);
    vh[(size_t)row * DH + lane + 64] = f2bf(y2);
  }
}

// ---------------- Flash attention: QBLK=96, 6 waves; fused Q rms+rope; setprio ----------------
template <int WRITE_LO>
__global__ __launch_bounds__(384) void attn3(const float* __restrict__ Qf,
                                             const float* __restrict__ qnw,
                                             const float* __restrict__ cosp,
                                             const float* __restrict__ sinp,
                                             const unsigned short* __restrict__ Kh,
                                             const unsigned short* __restrict__ Kl,
                                             const unsigned short* __restrict__ Vth,
                                             unsigned short* __restrict__ Oh,
                                             unsigned short* __restrict__ Ol,
                                             const int* __restrict__ cu, int ncu) {
  __shared__ unsigned short kh_lds[32][136];
  __shared__ unsigned short kl_lds[32][136];
  __shared__ unsigned short vh_lds[144][40];
  __shared__ unsigned short ph_lds[6][16][40];

  int id = blockIdx.y * gridDim.x + blockIdx.x;
  int nid = (id & 7) * 64 + (id >> 3);
  const int qt = nid & 31, h = nid >> 5;
  const int qbase = qt * 96;
  const int kvh = h >> 1;
  const int tid = threadIdx.x, lane = tid & 63, wave = tid >> 6;
  const int g = lane >> 4, r16 = lane & 15;

  for (int i = tid; i < 16 * 40; i += 384) {
    int rr = i / 40, cc = i % 40;
    vh_lds[128 + rr][cc] = (rr == 0) ? (unsigned short)0x3F80 : (unsigned short)0;
  }

  bf16x8 aqh[4], aql[4];
  {
    int q_r = qbase + wave * 16 + r16;
    const float* xq = Qf + (size_t)q_r * HIDDEN + h * DH;
    float xv[4][8];
    float ss = 0.f;
#pragma unroll
    for (int ks = 0; ks < 4; ++ks) {
      f32x4 a = *(const f32x4*)(xq + ks * 32 + g * 8);
      f32x4 b = *(const f32x4*)(xq + ks * 32 + g * 8 + 4);
#pragma unroll
      for (int j = 0; j < 4; ++j) { xv[ks][j] = a[j]; xv[ks][4 + j] = b[j]; }
#pragma unroll
      for (int j = 0; j < 8; ++j) ss += xv[ks][j] * xv[ks][j];
    }
    ss += __shfl_xor(ss, 16, 64);
    ss += __shfl_xor(ss, 32, 64);
    float inv = rsqrtf(ss * (1.0f / 128.0f) + 1e-6f);
    float y[4][8];
#pragma unroll
    for (int ks = 0; ks < 4; ++ks) {
      f32x4 w0 = *(const f32x4*)(qnw + ks * 32 + g * 8);
      f32x4 w1 = *(const f32x4*)(qnw + ks * 32 + g * 8 + 4);
#pragma unroll
      for (int j = 0; j < 4; ++j) {
        y[ks][j] = xv[ks][j] * inv * w0[j];
        y[ks][4 + j] = xv[ks][4 + j] * inv * w1[j];
      }
    }
    const float* cb = cosp + (size_t)q_r * DH;
    const float* sb = sinp + (size_t)q_r * DH;
#pragma unroll
    for (int ks = 0; ks < 4; ++ks) {
      bf16x8 th, tl;
#pragma unroll
      for (int j2 = 0; j2 < 2; ++j2) {
        int col = ks * 32 + g * 8 + j2 * 4;
        f32x4 cv = *(const f32x4*)(cb + col);
        f32x4 sv = *(const f32x4*)(sb + col);
#pragma unroll
        for (int j = 0; j < 4; ++j) {
          float o;
          if (ks < 2) o = y[ks][j2 * 4 + j] * cv[j] - y[ks + 2][j2 * 4 + j] * sv[j];
          else        o = y[ks][j2 * 4 + j] * cv[j] + y[ks - 2][j2 * 4 + j] * sv[j];
          unsigned short hx, lx;
          split2(o, hx, lx);
          th[j2 * 4 + j] = (short)hx;
          tl[j2 * 4 + j] = (short)lx;
        }
      }
      aqh[ks] = th; aql[ks] = tl;
    }
  }

  int ssr[4];
#pragma unroll
  for (int r = 0; r < 4; ++r) {
    int q_r = qbase + wave * 16 + g * 4 + r;
    int s = 0;
    for (int i = 1; i < ncu; ++i) { int v = cu[i]; if (v <= q_r) s = v; }
    ssr[r] = s;
  }
  int ss_base = 0;
  for (int i = 1; i < ncu; ++i) { int v = cu[i]; if (v <= qbase) ss_base = v; }

  float m_r[4] = {-1e30f, -1e30f, -1e30f, -1e30f};
  f32x4 oacc[8];
#pragma unroll
  for (int db = 0; db < 8; ++db) oacc[db] = (f32x4){0.f, 0.f, 0.f, 0.f};
  f32x4 oaccL = (f32x4){0.f, 0.f, 0.f, 0.f};

  int lo = qbase - WINDOW + 1;
  if (lo < ss_base) lo = ss_base;
  if (lo < 0) lo = 0;
  int kt0 = lo & ~31;
  int ktend = qbase + 95;

  const bool stager = tid < 256;
  const int krow = (tid & 255) >> 3, kc = tid & 7;
  const int vd = (tid & 255) >> 1, vhalf = (tid & 1) * 16;
  const int qmin = qbase + wave * 16;
  const int sw0 = ((kc + 2 * (krow & 15)) & 15) * 16;
  const int sw1 = ((kc + 8 + 2 * (krow & 15)) & 15) * 16;

  ushort8 rkh0, rkh1, rkl0, rkl1, rvh0, rvh1;
  auto loadTile = [&](int kt) {
    if (!stager) return;
    size_t goff = ((size_t)(kt + krow) * NHKV + kvh) * DH + kc * 8;
    rkh0 = *(const ushort8*)(Kh + goff);
    rkh1 = *(const ushort8*)(Kh + goff + 64);
    rkl0 = *(const ushort8*)(Kl + goff);
    rkl1 = *(const ushort8*)(Kl + goff + 64);
    size_t voff = ((size_t)kvh * DH + vd) * T_TOK + kt + vhalf;
    rvh0 = *(const ushort8*)(Vth + voff);
    rvh1 = *(const ushort8*)(Vth + voff + 8);
  };
  auto writeTile = [&]() {
    if (!stager) return;
    char* kbh = (char*)&kh_lds[krow][0];
    char* kbl = (char*)&kl_lds[krow][0];
    *(ushort8*)(kbh + sw0) = rkh0;
    *(ushort8*)(kbh + sw1) = rkh1;
    *(ushort8*)(kbl + sw0) = rkl0;
    *(ushort8*)(kbl + sw1) = rkl1;
    *(ushort8*)&vh_lds[vd][vhalf] = rvh0;
    *(ushort8*)&vh_lds[vd][vhalf + 8] = rvh1;
  };

  loadTile(kt0);
  writeTile();
  __syncthreads();

  for (int kt = kt0; kt <= ktend; kt += 32) {
    const bool hasNext = (kt + 32 <= ktend);
    if (hasNext) loadTile(kt + 32);

    f32x4 s0 = (f32x4){0.f, 0.f, 0.f, 0.f}, s1 = (f32x4){0.f, 0.f, 0.f, 0.f};
    {
      const char* kb0h = (const char*)&kh_lds[r16][0];
      const char* kb1h = (const char*)&kh_lds[16 + r16][0];
      const char* kb0l = (const char*)&kl_lds[r16][0];
      const char* kb1l = (const char*)&kl_lds[16 + r16][0];
      __builtin_amdgcn_s_setprio(1);
#pragma unroll
      for (int ks = 0; ks < 4; ++ks) {
        int sl = ((ks * 4 + g + 2 * r16) & 15) * 16;
        bf16x8 bh0 = *(const bf16x8*)(kb0h + sl);
        bf16x8 bh1 = *(const bf16x8*)(kb1h + sl);
        bf16x8 bl0 = *(const bf16x8*)(kb0l + sl);
        bf16x8 bl1 = *(const bf16x8*)(kb1l + sl);
        s0 = __builtin_amdgcn_mfma_f32_16x16x32_bf16(aqh[ks], bh0, s0, 0, 0, 0);
        s0 = __builtin_amdgcn_mfma_f32_16x16x32_bf16(aqh[ks], bl0, s0, 0, 0, 0);
        s0 = __builtin_amdgcn_mfma_f32_16x16x32_bf16(aql[ks], bh0, s0, 0, 0, 0);
        s1 = __builtin_amdgcn_mfma_f32_16x16x32_bf16(aqh[ks], bh1, s1, 0, 0, 0);
        s1 = __builtin_amdgcn_mfma_f32_16x16x32_bf16(aqh[ks], bl1, s1, 0, 0, 0);
        s1 = __builtin_amdgcn_mfma_f32_16x16x32_bf16(aql[ks], bh1, s1, 0, 0, 0);
      }
      __builtin_amdgcn_s_setprio(0);
    }

    float sv0_[4], sv1_[4], mt_[4];
    bool ok0_[4], ok1_[4];
    bool interior = (kt + 31 <= qmin) && (kt >= qmin + 16 - WINDOW) &&
                    __all(kt >= ssr[3]);
    if (interior) {
#pragma unroll
      for (int r = 0; r < 4; ++r) {
        ok0_[r] = ok1_[r] = true;
        sv0_[r] = s0[r]; sv1_[r] = s1[r];
      }
    } else {
#pragma unroll
      for (int r = 0; r < 4; ++r) {
        int q_r = qmin + g * 4 + r;
        int k0 = kt + r16, k1 = k0 + 16;
        ok0_[r] = (k0 <= q_r) && (k0 > q_r - WINDOW) && (k0 >= ssr[r]);
        ok1_[r] = (k1 <= q_r) && (k1 > q_r - WINDOW) && (k1 >= ssr[r]);
        sv0_[r] = ok0_[r] ? s0[r] : -1e30f;
        sv1_[r] = ok1_[r] ? s1[r] : -1e30f;
      }
    }
#pragma unroll
    for (int r = 0; r < 4; ++r) {
      float mt = fmaxf(sv0_[r], sv1_[r]);
#pragma unroll
      for (int mm = 1; mm < 16; mm <<= 1) mt = fmaxf(mt, __shfl_xor(mt, mm, 64));
      mt_[r] = mt;
    }
    float grow = fmaxf(fmaxf(mt_[0] - m_r[0], mt_[1] - m_r[1]),
                       fmaxf(mt_[2] - m_r[2], mt_[3] - m_r[3]));
    if (!__all(grow <= 8.0f)) {
#pragma unroll
      for (int r = 0; r < 4; ++r) {
        float mnew = fmaxf(m_r[r], mt_[r]);
        float alpha = __expf(m_r[r] - mnew);
        m_r[r] = mnew;
#pragma unroll
        for (int db = 0; db < 8; ++db) oacc[db][r] *= alpha;
        oaccL[r] *= alpha;
      }
    }
#pragma unroll
    for (int r = 0; r < 4; ++r) {
      float p0v = ok0_[r] ? __expf(sv0_[r] - m_r[r]) : 0.f;
      float p1v = ok1_[r] ? __expf(sv1_[r] - m_r[r]) : 0.f;
      ph_lds[wave][g * 4 + r][r16] = f2bf(p0v);
      ph_lds[wave][g * 4 + r][16 + r16] = f2bf(p1v);
    }

    bf16x8 pah = *(const bf16x8*)&ph_lds[wave][r16][g * 8];
    __builtin_amdgcn_s_setprio(1);
#pragma unroll
    for (int db = 0; db < 8; ++db) {
      bf16x8 vfh = *(const bf16x8*)&vh_lds[db * 16 + r16][g * 8];
      oacc[db] = __builtin_amdgcn_mfma_f32_16x16x32_bf16(pah, vfh, oacc[db], 0, 0, 0);
    }
    {
      bf16x8 vfo = *(const bf16x8*)&vh_lds[128 + r16][g * 8];
      oaccL = __builtin_amdgcn_mfma_f32_16x16x32_bf16(pah, vfo, oaccL, 0, 0, 0);
    }
    __builtin_amdgcn_s_setprio(0);

    __syncthreads();
    if (hasNext) writeTile();
    __syncthreads();
  }

#pragma unroll
  for (int r = 0; r < 4; ++r) {
    int q_r = qbase + wave * 16 + g * 4 + r;
    float lsum = __shfl(oaccL[r], lane & 48, 64);
    float invl = 1.f / lsum;
#pragma unroll
    for (int db = 0; db < 8; ++db) {
      float ov = oacc[db][r] * invl;
      unsigned short hh, ll;
      split2(ov, hh, ll);
      Oh[(size_t)q_r * (NHQ * DH) + h * DH + db * 16 + r16] = hh;
      if (WRITE_LO) Ol[(size_t)q_r * (NHQ * DH) + h * DH + db * 16 + r16] = ll;
    }
  }
}

extern "C" void kernel_launch(void* const* d_in, const int* in_sizes, int n_in,
                              void* d_out, int out_size, void* d_ws, size_t ws_size,
                              hipStream_t stream) {
  const float* hidden = (const float*)d_in[0];
  const float* cosp   = (const float*)d_in[1];
  const float* sinp   = (const float*)d_in[2];
  const float* wq0    = (const float*)d_in[3];
  const float* wk0    = (const float*)d_in[4];
  const float* wv0    = (const float*)d_in[5];
  const float* wo0    = (const float*)d_in[6];
  const float* qn0    = (const float*)d_in[7];
  const float* kn0    = (const float*)d_in[8];
  const float* wq1    = (const float*)d_in[9];
  const float* wo1    = (const float*)d_in[10];
  const float* qn1    = (const float*)d_in[11];
  const int*   cu     = (const int*)d_in[12];
  int ncu = in_sizes[12];
  (void)n_in; (void)out_size; (void)ws_size;

  char* p = (char*)d_ws;
  auto alloc = [&](size_t bytes) { char* r = p; p += (bytes + 255) & ~255ull; return r; };

  unsigned short* wqkvh = (unsigned short*)alloc((size_t)2 * HIDDEN * HIDDEN * 2);
  unsigned short* wqkvl = (unsigned short*)alloc((size_t)2 * HIDDEN * HIDDEN * 2);
  unsigned short* wo0sh = (unsigned short*)alloc((size_t)HIDDEN * HIDDEN * 2);
  unsigned short* wo0sl = (unsigned short*)alloc((size_t)HIDDEN * HIDDEN * 2);
  unsigned short* wq1th = (unsigned short*)alloc((size_t)HIDDEN * HIDDEN * 2);
  unsigned short* wq1tl = (unsigned short*)alloc((size_t)HIDDEN * HIDDEN * 2);
  unsigned short* wo1t  = (unsigned short*)alloc((size_t)HIDDEN * HIDDEN * 2);
  float*          c32q  = (float*)alloc((size_t)T_TOK * HIDDEN * 4);  // Q fp32 -> later W01 hi/lo
  float*          c32kv = (float*)alloc((size_t)T_TOK * HIDDEN * 4);  // KV fp32 -> later q1_pre fp32
  unsigned short* xh    = (unsigned short*)alloc((size_t)T_TOK * HIDDEN * 2);
  unsigned short* xl    = (unsigned short*)alloc((size_t)T_TOK * HIDDEN * 2);
  unsigned short* kh    = (unsigned short*)alloc((size_t)T_TOK * KVN * 2);
  unsigned short* kl    = (unsigned short*)alloc((size_t)T_TOK * KVN * 2);
  unsigned short* vh    = (unsigned short*)alloc((size_t)T_TOK * KVN * 2);
  unsigned short* vth   = (unsigned short*)alloc((size_t)T_TOK * KVN * 2);

  unsigned short* W01th = (unsigned short*)c32q;
  unsigned short* W01tl = W01th + (size_t)HIDDEN * HIDDEN;

  // 1. all independent preprocessing in ONE launch (incl. wo1 transpose)
  prep<<<26624, 256, 0, stream>>>(hidden, wq0, wk0, wv0, wo0, wq1, wo1,
                                  xh, xl, wqkvh, wqkvl, wo0sh, wo0sl, wq1th, wq1tl, wo1t);

  // 2. mega-fused QKV projection (uniform 3-term, r15-proven 149us config)
  gemm3_128<<<dim3(T_TOK / 128, 4096 / 128), 256, 0, stream>>>(
      xh, xl, wqkvh, wqkvl, c32q, c32kv, HIDDEN, T_TOK, 4096, HIDDEN);

  // 3. K/V norms + V transpose
  rms_kv<<<2 * T_TOK * NHKV / 4, 256, 0, stream>>>(c32kv, kn0, cosp, sinp, kh, kl, vh);
  transpose_u16<<<dim3(KVN / 32, T_TOK / 32), 256, 0, stream>>>(vh, vth, T_TOK, KVN);

  // 4. attn0 (fused Q-rms from c32q) -> o0 in xh/xl
  attn3<1><<<dim3(32, 16), 384, 0, stream>>>(c32q, qn0, cosp, sinp, kh, kl, vth, xh, xl, cu, ncu);

  // 5. W01t = wq1^T · wo0^T (512 blocks = 2/CU); into c32q region (Q dead)
  gemm3_64<<<dim3(HIDDEN / 64, HIDDEN / 128), 256, 0, stream>>>(
      wq1th, wq1tl, wo0sh, wo0sl, W01th, W01tl, HIDDEN, HIDDEN, HIDDEN);

  // 6. q1_pre = o0 @ W01 -> c32kv (KV fp32 dead)
  gemm3_96<<<dim3(T_TOK / 96, HIDDEN / 128), 256, 0, stream>>>(
      xh, xl, W01th, W01tl, c32kv, T_TOK, HIDDEN, HIDDEN);

  // 7. attn1 -> xh (hi only)
  attn3<0><<<dim3(32, 16), 384, 0, stream>>>(c32kv, qn1, cosp, sinp, kh, kl, vth, xh, nullptr, cu, ncu);

  // 8. final projection (1-term, linear path)
  gemm1_96<<<dim3(T_TOK / 96, HIDDEN / 128), 256, 0, stream>>>(xh, wo1t, (float*)d_out, T_TOK, HIDDEN, HIDDEN);
}

// Round 18
// 602.453 us; speedup vs baseline: 1.1311x; 1.0921x over previous
//
#include <hip/hip_runtime.h>
#include <hip/hip_bf16.h>

#define T_TOK 3072
#define HIDDEN 2048
#define NHQ 16
#define NHKV 8
#define DH 128
#define WINDOW 1024
#define KVN 1024

typedef __attribute__((ext_vector_type(4))) float f32x4;
typedef __attribute__((ext_vector_type(8))) short bf16x8;
typedef __attribute__((ext_vector_type(8))) unsigned short ushort8;
typedef __attribute__((ext_vector_type(4))) unsigned short ushort4v;

__device__ __forceinline__ unsigned short f2bf(float f) {
  union { float fv; unsigned u; } v; v.fv = f;
  unsigned r = v.u + 0x7fffu + ((v.u >> 16) & 1u);
  return (unsigned short)(r >> 16);
}
__device__ __forceinline__ float bf2f(unsigned short h) {
  union { unsigned u; float f; } v; v.u = ((unsigned)h) << 16;
  return v.f;
}
__device__ __forceinline__ void split2(float f, unsigned short& hi, unsigned short& lo) {
  hi = f2bf(f);
  lo = f2bf(f - bf2f(hi));
}

// ---------------- mega-prep: ALL independent input preprocessing in ONE launch ----------------
__global__ __launch_bounds__(256) void prep(const float* __restrict__ hidden,
                                            const float* __restrict__ wq0,
                                            const float* __restrict__ wk0,
                                            const float* __restrict__ wv0,
                                            const float* __restrict__ wo0,
                                            const float* __restrict__ wq1,
                                            const float* __restrict__ wo1,
                                            unsigned short* __restrict__ xh,
                                            unsigned short* __restrict__ xl,
                                            unsigned short* __restrict__ wqkvh,
                                            unsigned short* __restrict__ wqkvl,
                                            unsigned short* __restrict__ wo0sh,
                                            unsigned short* __restrict__ wo0sl,
                                            unsigned short* __restrict__ wq1th,
                                            unsigned short* __restrict__ wq1tl,
                                            unsigned short* __restrict__ wo1th) {
  __shared__ float tile[32][33];
  const int K = HIDDEN;
  int id = blockIdx.x;
  if (id < 6144 || (id >= 14336 && id < 18432)) {
    const float* src; unsigned short *dh, *dl; int local;
    if (id < 6144) { src = hidden; dh = xh; dl = xl; local = id; }
    else           { src = wo0; dh = wo0sh; dl = wo0sl; local = id - 14336; }
    int i = (local * 256 + threadIdx.x) * 4;
    f32x4 v = *(const f32x4*)(src + i);
    ushort4v oh, ol;
#pragma unroll
    for (int j = 0; j < 4; ++j) {
      unsigned short h, l;
      split2(v[j], h, l);
      oh[j] = h; ol[j] = l;
    }
    *(ushort4v*)(dh + i) = oh;
    *(ushort4v*)(dl + i) = ol;
    return;
  }
  const float* W; int N, local; unsigned short *Dh, *Dl; size_t dstoff;
  if (id < 14336) {
    int lid = id - 6144;
    if (lid < 4096)      { W = wq0; N = 2048; local = lid;        dstoff = 0; }
    else if (lid < 6144) { W = wk0; N = 1024; local = lid - 4096; dstoff = (size_t)2048 * K; }
    else                 { W = wv0; N = 1024; local = lid - 6144; dstoff = (size_t)3072 * K; }
    Dh = wqkvh; Dl = wqkvl;
  } else if (id < 22528) {
    W = wq1; N = 2048; local = id - 18432; dstoff = 0;
    Dh = wq1th; Dl = wq1tl;
  } else {
    W = wo1; N = 2048; local = id - 22528; dstoff = 0;
    Dh = wo1th; Dl = nullptr;
  }
  int ntc = N / 32;
  int bn = (local % ntc) * 32, bk = (local / ntc) * 32;
  int tx = threadIdx.x & 31, ty = threadIdx.x >> 5;
#pragma unroll
  for (int i = 0; i < 4; ++i)
    tile[ty + i * 8][tx] = W[(size_t)(bk + ty + i * 8) * N + bn + tx];
  __syncthreads();
#pragma unroll
  for (int i = 0; i < 4; ++i) {
    unsigned short h, l;
    split2(tile[tx][ty + i * 8], h, l);
    Dh[dstoff + (size_t)(bn + ty + i * 8) * K + bk + tx] = h;
    if (Dl) Dl[dstoff + (size_t)(bn + ty + i * 8) * K + bk + tx] = l;
  }
}

// ---------------- generic u16 transpose ----------------
__global__ __launch_bounds__(256) void transpose_u16(const unsigned short* __restrict__ src,
                                                     unsigned short* __restrict__ dst,
                                                     int R, int C) {
  __shared__ unsigned short tile[32][33];
  int bc = blockIdx.x * 32, br = blockIdx.y * 32;
  int tx = threadIdx.x & 31, ty = threadIdx.x >> 5;
#pragma unroll
  for (int i = 0; i < 4; ++i)
    tile[ty + i * 8][tx] = src[(size_t)(br + ty + i * 8) * C + bc + tx];
  __syncthreads();
#pragma unroll
  for (int i = 0; i < 4; ++i)
    dst[(size_t)(bc + ty + i * 8) * R + br + tx] = tile[tx][ty + i * 8];
}

#define GSLOT(lane) ((((lane) & 3) + 4 - (((lane) >> 3) & 3)) & 3)

// ---------------- 3-term split GEMM, 128x128 tile (dual fp32 out) ----------------
__global__ __launch_bounds__(256) void gemm3_128(const unsigned short* __restrict__ Ah,
                                                 const unsigned short* __restrict__ Al,
                                                 const unsigned short* __restrict__ Bh,
                                                 const unsigned short* __restrict__ Bl,
                                                 float* __restrict__ Cq,
                                                 float* __restrict__ Ckv,
                                                 int strd, int M, int N, int K) {
  __shared__ unsigned short ah_lds[128 * 32];
  __shared__ unsigned short al_lds[128 * 32];
  __shared__ unsigned short bh_lds[128 * 32];
  __shared__ unsigned short bl_lds[128 * 32];
  const int tid = threadIdx.x, lane = tid & 63, wave = tid >> 6;
  const int wr = (wave >> 1) * 64, wc = (wave & 1) * 64;
  const int g = lane >> 4, r16 = lane & 15;
  int nwg = gridDim.x * gridDim.y;
  int id = blockIdx.y * gridDim.x + blockIdx.x;
  int nid = (id & 7) * (nwg >> 3) + (id >> 3);
  const int bm = nid % gridDim.x, bn = nid / gridDim.x;
  f32x4 acc[4][4];
#pragma unroll
  for (int i = 0; i < 4; ++i)
#pragma unroll
    for (int j = 0; j < 4; ++j) acc[i][j] = (f32x4){0.f, 0.f, 0.f, 0.f};

  const unsigned short* AhB = Ah + (size_t)bm * 128 * K;
  const unsigned short* AlB = Al + (size_t)bm * 128 * K;
  const unsigned short* BhB = Bh + (size_t)bn * 128 * K;
  const unsigned short* BlB = Bl + (size_t)bn * 128 * K;

  const int slg = GSLOT(lane) * 8;
  const int sr = ((r16 >> 1) & 3);

  for (int kt = 0; kt < K; kt += 32) {
    __syncthreads();
#pragma unroll
    for (int c = 0; c < 2; ++c) {
      size_t goff = (size_t)(wave * 32 + c * 16 + (lane >> 2)) * K + kt + slg;
      int loff = (wave * 2 + c) * 512;
      __builtin_amdgcn_global_load_lds(
          (const __attribute__((address_space(1))) unsigned int*)(AhB + goff),
          (__attribute__((address_space(3))) unsigned int*)(ah_lds + loff), 16, 0, 0);
      __builtin_amdgcn_global_load_lds(
          (const __attribute__((address_space(1))) unsigned int*)(AlB + goff),
          (__attribute__((address_space(3))) unsigned int*)(al_lds + loff), 16, 0, 0);
      __builtin_amdgcn_global_load_lds(
          (const __attribute__((address_space(1))) unsigned int*)(BhB + goff),
          (__attribute__((address_space(3))) unsigned int*)(bh_lds + loff), 16, 0, 0);
      __builtin_amdgcn_global_load_lds(
          (const __attribute__((address_space(1))) unsigned int*)(BlB + goff),
          (__attribute__((address_space(3))) unsigned int*)(bl_lds + loff), 16, 0, 0);
    }
    __syncthreads();
    bf16x8 ahf[4], alf[4], bhf[4], blf[4];
    int sa = ((g + sr) & 3) * 8;
#pragma unroll
    for (int i = 0; i < 4; ++i) {
      ahf[i] = *(const bf16x8*)&ah_lds[(wr + i * 16 + r16) * 32 + sa];
      alf[i] = *(const bf16x8*)&al_lds[(wr + i * 16 + r16) * 32 + sa];
      bhf[i] = *(const bf16x8*)&bh_lds[(wc + i * 16 + r16) * 32 + sa];
      blf[i] = *(const bf16x8*)&bl_lds[(wc + i * 16 + r16) * 32 + sa];
    }
#pragma unroll
    for (int i = 0; i < 4; ++i)
#pragma unroll
      for (int j = 0; j < 4; ++j) {
        acc[i][j] = __builtin_amdgcn_mfma_f32_16x16x32_bf16(ahf[i], bhf[j], acc[i][j], 0, 0, 0);
        acc[i][j] = __builtin_amdgcn_mfma_f32_16x16x32_bf16(ahf[i], blf[j], acc[i][j], 0, 0, 0);
        acc[i][j] = __builtin_amdgcn_mfma_f32_16x16x32_bf16(alf[i], bhf[j], acc[i][j], 0, 0, 0);
      }
  }

#pragma unroll
  for (int i = 0; i < 4; ++i) {
    int row = bm * 128 + wr + i * 16 + g * 4;
#pragma unroll
    for (int j = 0; j < 4; ++j) {
      int colg = bn * 128 + wc + j * 16 + r16;
      float* Cb; int cc;
      if (colg < 2048) { Cb = Cq; cc = colg; } else { Cb = Ckv; cc = colg - 2048; }
#pragma unroll
      for (int r = 0; r < 4; ++r)
        Cb[(size_t)(row + r) * strd + cc] = acc[i][j][r];
    }
  }
}

// ---------------- 3-term split GEMM, 64x128 tile, hi/lo bf16 out (W01) ----------------
__global__ __launch_bounds__(256) void gemm3_64(const unsigned short* __restrict__ Ah,
                                                const unsigned short* __restrict__ Al,
                                                const unsigned short* __restrict__ Bh,
                                                const unsigned short* __restrict__ Bl,
                                                unsigned short* __restrict__ Ch,
                                                unsigned short* __restrict__ Cl,
                                                int M, int N, int K) {
  __shared__ unsigned short ah_lds[64 * 32];
  __shared__ unsigned short al_lds[64 * 32];
  __shared__ unsigned short bh_lds[128 * 32];
  __shared__ unsigned short bl_lds[128 * 32];
  const int tid = threadIdx.x, lane = tid & 63, wave = tid >> 6;
  const int wr = (wave >> 1) * 32, wc = (wave & 1) * 64;
  const int g = lane >> 4, r16 = lane & 15;
  int nwg = gridDim.x * gridDim.y;
  int id = blockIdx.y * gridDim.x + blockIdx.x;
  int nid = (id & 7) * (nwg >> 3) + (id >> 3);
  const int bm = nid % gridDim.x, bn = nid / gridDim.x;
  f32x4 acc[2][4];
#pragma unroll
  for (int i = 0; i < 2; ++i)
#pragma unroll
    for (int j = 0; j < 4; ++j) acc[i][j] = (f32x4){0.f, 0.f, 0.f, 0.f};

  const unsigned short* AhB = Ah + (size_t)bm * 64 * K;
  const unsigned short* AlB = Al + (size_t)bm * 64 * K;
  const unsigned short* BhB = Bh + (size_t)bn * 128 * K;
  const unsigned short* BlB = Bl + (size_t)bn * 128 * K;

  const int slg = GSLOT(lane) * 8;
  const int sr = ((r16 >> 1) & 3);

  for (int kt = 0; kt < K; kt += 32) {
    __syncthreads();
    {
      size_t goff = (size_t)(wave * 16 + (lane >> 2)) * K + kt + slg;
      __builtin_amdgcn_global_load_lds(
          (const __attribute__((address_space(1))) unsigned int*)(AhB + goff),
          (__attribute__((address_space(3))) unsigned int*)(ah_lds + wave * 512), 16, 0, 0);
      __builtin_amdgcn_global_load_lds(
          (const __attribute__((address_space(1))) unsigned int*)(AlB + goff),
          (__attribute__((address_space(3))) unsigned int*)(al_lds + wave * 512), 16, 0, 0);
    }
#pragma unroll
    for (int c = 0; c < 2; ++c) {
      size_t goff = (size_t)(wave * 32 + c * 16 + (lane >> 2)) * K + kt + slg;
      int loff = (wave * 2 + c) * 512;
      __builtin_amdgcn_global_load_lds(
          (const __attribute__((address_space(1))) unsigned int*)(BhB + goff),
          (__attribute__((address_space(3))) unsigned int*)(bh_lds + loff), 16, 0, 0);
      __builtin_amdgcn_global_load_lds(
          (const __attribute__((address_space(1))) unsigned int*)(BlB + goff),
          (__attribute__((address_space(3))) unsigned int*)(bl_lds + loff), 16, 0, 0);
    }
    __syncthreads();
    bf16x8 ahf[2], alf[2], bhf[4], blf[4];
    int sa = ((g + sr) & 3) * 8;
#pragma unroll
    for (int i = 0; i < 2; ++i) {
      ahf[i] = *(const bf16x8*)&ah_lds[(wr + i * 16 + r16) * 32 + sa];
      alf[i] = *(const bf16x8*)&al_lds[(wr + i * 16 + r16) * 32 + sa];
    }
#pragma unroll
    for (int j = 0; j < 4; ++j) {
      bhf[j] = *(const bf16x8*)&bh_lds[(wc + j * 16 + r16) * 32 + sa];
      blf[j] = *(const bf16x8*)&bl_lds[(wc + j * 16 + r16) * 32 + sa];
    }
#pragma unroll
    for (int i = 0; i < 2; ++i)
#pragma unroll
      for (int j = 0; j < 4; ++j) {
        acc[i][j] = __builtin_amdgcn_mfma_f32_16x16x32_bf16(ahf[i], bhf[j], acc[i][j], 0, 0, 0);
        acc[i][j] = __builtin_amdgcn_mfma_f32_16x16x32_bf16(ahf[i], blf[j], acc[i][j], 0, 0, 0);
        acc[i][j] = __builtin_amdgcn_mfma_f32_16x16x32_bf16(alf[i], bhf[j], acc[i][j], 0, 0, 0);
      }
  }

#pragma unroll
  for (int i = 0; i < 2; ++i) {
    int row = bm * 64 + wr + i * 16 + g * 4;
#pragma unroll
    for (int j = 0; j < 4; ++j) {
      int col = bn * 128 + wc + j * 16 + r16;
#pragma unroll
      for (int r = 0; r < 4; ++r) {
        unsigned short h, l;
        split2(acc[i][j][r], h, l);
        Ch[(size_t)(row + r) * N + col] = h;
        Cl[(size_t)(row + r) * N + col] = l;
      }
    }
  }
}

// ---------------- 3-term split GEMM, 96x128 tile (fp32 out) ----------------
__global__ __launch_bounds__(256) void gemm3_96(const unsigned short* __restrict__ Ah,
                                                const unsigned short* __restrict__ Al,
                                                const unsigned short* __restrict__ Bh,
                                                const unsigned short* __restrict__ Bl,
                                                float* __restrict__ Cf,
                                                int M, int N, int K) {
  __shared__ unsigned short ah_lds[96 * 32];
  __shared__ unsigned short al_lds[96 * 32];
  __shared__ unsigned short bh_lds[128 * 32];
  __shared__ unsigned short bl_lds[128 * 32];
  const int tid = threadIdx.x, lane = tid & 63, wave = tid >> 6;
  const int wr = (wave >> 1) * 48, wc = (wave & 1) * 64;
  const int g = lane >> 4, r16 = lane & 15;
  int nwg = gridDim.x * gridDim.y;
  int id = blockIdx.y * gridDim.x + blockIdx.x;
  int nid = (id & 7) * (nwg >> 3) + (id >> 3);
  const int bm = nid % gridDim.x, bn = nid / gridDim.x;
  f32x4 acc[3][4];
#pragma unroll
  for (int i = 0; i < 3; ++i)
#pragma unroll
    for (int j = 0; j < 4; ++j) acc[i][j] = (f32x4){0.f, 0.f, 0.f, 0.f};

  const unsigned short* AhB = Ah + (size_t)bm * 96 * K;
  const unsigned short* AlB = Al + (size_t)bm * 96 * K;
  const unsigned short* BhB = Bh + (size_t)bn * 128 * K;
  const unsigned short* BlB = Bl + (size_t)bn * 128 * K;

  const int slg = GSLOT(lane) * 8;
  const int sr = ((r16 >> 1) & 3);

  for (int kt = 0; kt < K; kt += 32) {
    __syncthreads();
    {
      int c = wave;
      size_t goff = (size_t)(c * 16 + (lane >> 2)) * K + kt + slg;
      __builtin_amdgcn_global_load_lds(
          (const __attribute__((address_space(1))) unsigned int*)(AhB + goff),
          (__attribute__((address_space(3))) unsigned int*)(ah_lds + c * 512), 16, 0, 0);
      __builtin_amdgcn_global_load_lds(
          (const __attribute__((address_space(1))) unsigned int*)(AlB + goff),
          (__attribute__((address_space(3))) unsigned int*)(al_lds + c * 512), 16, 0, 0);
      if (wave < 2) {
        int c2 = 4 + wave;
        size_t goff2 = (size_t)(c2 * 16 + (lane >> 2)) * K + kt + slg;
        __builtin_amdgcn_global_load_lds(
            (const __attribute__((address_space(1))) unsigned int*)(AhB + goff2),
            (__attribute__((address_space(3))) unsigned int*)(ah_lds + c2 * 512), 16, 0, 0);
        __builtin_amdgcn_global_load_lds(
            (const __attribute__((address_space(1))) unsigned int*)(AlB + goff2),
            (__attribute__((address_space(3))) unsigned int*)(al_lds + c2 * 512), 16, 0, 0);
      }
    }
#pragma unroll
    for (int c = 0; c < 2; ++c) {
      size_t goff = (size_t)(wave * 32 + c * 16 + (lane >> 2)) * K + kt + slg;
      int loff = (wave * 2 + c) * 512;
      __builtin_amdgcn_global_load_lds(
          (const __attribute__((address_space(1))) unsigned int*)(BhB + goff),
          (__attribute__((address_space(3))) unsigned int*)(bh_lds + loff), 16, 0, 0);
      __builtin_amdgcn_global_load_lds(
          (const __attribute__((address_space(1))) unsigned int*)(BlB + goff),
          (__attribute__((address_space(3))) unsigned int*)(bl_lds + loff), 16, 0, 0);
    }
    __syncthreads();
    bf16x8 ahf[3], alf[3], bhf[4], blf[4];
    int sa = ((g + sr) & 3) * 8;
#pragma unroll
    for (int i = 0; i < 3; ++i) {
      ahf[i] = *(const bf16x8*)&ah_lds[(wr + i * 16 + r16) * 32 + sa];
      alf[i] = *(const bf16x8*)&al_lds[(wr + i * 16 + r16) * 32 + sa];
    }
#pragma unroll
    for (int j = 0; j < 4; ++j) {
      bhf[j] = *(const bf16x8*)&bh_lds[(wc + j * 16 + r16) * 32 + sa];
      blf[j] = *(const bf16x8*)&bl_lds[(wc + j * 16 + r16) * 32 + sa];
    }
#pragma unroll
    for (int i = 0; i < 3; ++i)
#pragma unroll
      for (int j = 0; j < 4; ++j) {
        acc[i][j] = __builtin_amdgcn_mfma_f32_16x16x32_bf16(ahf[i], bhf[j], acc[i][j], 0, 0, 0);
        acc[i][j] = __builtin_amdgcn_mfma_f32_16x16x32_bf16(ahf[i], blf[j], acc[i][j], 0, 0, 0);
        acc[i][j] = __builtin_amdgcn_mfma_f32_16x16x32_bf16(alf[i], bhf[j], acc[i][j], 0, 0, 0);
      }
  }

#pragma unroll
  for (int i = 0; i < 3; ++i) {
    int row = bm * 96 + wr + i * 16 + g * 4;
#pragma unroll
    for (int j = 0; j < 4; ++j) {
      int col = bn * 128 + wc + j * 16 + r16;
#pragma unroll
      for (int r = 0; r < 4; ++r)
        Cf[(size_t)(row + r) * N + col] = acc[i][j][r];
    }
  }
}

// ---------------- 1-term bf16 GEMM, 96x128 tile ----------------
__global__ __launch_bounds__(256) void gemm1_96(const unsigned short* __restrict__ Ah,
                                                const unsigned short* __restrict__ Bh,
                                                float* __restrict__ Cf,
                                                int M, int N, int K) {
  __shared__ unsigned short ah_lds[96 * 32];
  __shared__ unsigned short bh_lds[128 * 32];
  const int tid = threadIdx.x, lane = tid & 63, wave = tid >> 6;
  const int wr = (wave >> 1) * 48, wc = (wave & 1) * 64;
  const int g = lane >> 4, r16 = lane & 15;
  int nwg = gridDim.x * gridDim.y;
  int id = blockIdx.y * gridDim.x + blockIdx.x;
  int nid = (id & 7) * (nwg >> 3) + (id >> 3);
  const int bm = nid % gridDim.x, bn = nid / gridDim.x;
  f32x4 acc[3][4];
#pragma unroll
  for (int i = 0; i < 3; ++i)
#pragma unroll
    for (int j = 0; j < 4; ++j) acc[i][j] = (f32x4){0.f, 0.f, 0.f, 0.f};

  const unsigned short* AhB = Ah + (size_t)bm * 96 * K;
  const unsigned short* BhB = Bh + (size_t)bn * 128 * K;

  const int slg = GSLOT(lane) * 8;
  const int sr = ((r16 >> 1) & 3);

  for (int kt = 0; kt < K; kt += 32) {
    __syncthreads();
    {
      int c = wave;
      size_t goff = (size_t)(c * 16 + (lane >> 2)) * K + kt + slg;
      __builtin_amdgcn_global_load_lds(
          (const __attribute__((address_space(1))) unsigned int*)(AhB + goff),
          (__attribute__((address_space(3))) unsigned int*)(ah_lds + c * 512), 16, 0, 0);
      if (wave < 2) {
        int c2 = 4 + wave;
        size_t goff2 = (size_t)(c2 * 16 + (lane >> 2)) * K + kt + slg;
        __builtin_amdgcn_global_load_lds(
            (const __attribute__((address_space(1))) unsigned int*)(AhB + goff2),
            (__attribute__((address_space(3))) unsigned int*)(ah_lds + c2 * 512), 16, 0, 0);
      }
    }
#pragma unroll
    for (int c = 0; c < 2; ++c) {
      size_t goff = (size_t)(wave * 32 + c * 16 + (lane >> 2)) * K + kt + slg;
      __builtin_amdgcn_global_load_lds(
          (const __attribute__((address_space(1))) unsigned int*)(BhB + goff),
          (__attribute__((address_space(3))) unsigned int*)(bh_lds + (wave * 2 + c) * 512), 16, 0, 0);
    }
    __syncthreads();
    bf16x8 ahf[3], bhf[4];
    int sa = ((g + sr) & 3) * 8;
#pragma unroll
    for (int i = 0; i < 3; ++i)
      ahf[i] = *(const bf16x8*)&ah_lds[(wr + i * 16 + r16) * 32 + sa];
#pragma unroll
    for (int j = 0; j < 4; ++j)
      bhf[j] = *(const bf16x8*)&bh_lds[(wc + j * 16 + r16) * 32 + sa];
#pragma unroll
    for (int i = 0; i < 3; ++i)
#pragma unroll
      for (int j = 0; j < 4; ++j)
        acc[i][j] = __builtin_amdgcn_mfma_f32_16x16x32_bf16(ahf[i], bhf[j], acc[i][j], 0, 0, 0);
  }

#pragma unroll
  for (int i = 0; i < 3; ++i) {
    int row = bm * 96 + wr + i * 16 + g * 4;
#pragma unroll
    for (int j = 0; j < 4; ++j) {
      int col = bn * 128 + wc + j * 16 + r16;
#pragma unroll
      for (int r = 0; r < 4; ++r)
        Cf[(size_t)(row + r) * N + col] = acc[i][j][r];
    }
  }
}

// ---------------- merged K+V RMSNorm ----------------
__global__ __launch_bounds__(256) void rms_kv(const float* __restrict__ X,
                                              const float* __restrict__ kn,
                                              const float* __restrict__ cosp,
                                              const float* __restrict__ sinp,
                                              unsigned short* __restrict__ kh,
                                              unsigned short* __restrict__ kl,
                                              unsigned short* __restrict__ vh) {
  const int half = T_TOK * NHKV / 4;
  bool isV = (int)blockIdx.x >= half;
  int bid = isV ? blockIdx.x - half : blockIdx.x;
  int row = bid * 4 + (threadIdx.x >> 6);
  int lane = threadIdx.x & 63;
  int t = row >> 3, hh_ = row & 7;
  const float* x = X + (size_t)t * HIDDEN + (isV ? KVN : 0) + (size_t)hh_ * DH;
  float x1 = x[lane], x2 = x[lane + 64];
  float ss = x1 * x1 + x2 * x2;
#pragma unroll
  for (int m = 1; m < 64; m <<= 1) ss += __shfl_xor(ss, m, 64);
  float inv = rsqrtf(ss * (1.0f / 128.0f) + 1e-6f);
  float y1 = x1 * inv, y2 = x2 * inv;
  if (!isV) {
    y1 *= kn[lane]; y2 *= kn[lane + 64];
    float c1 = cosp[t * DH + lane], s1 = sinp[t * DH + lane];
    float c2 = cosp[t * DH + lane + 64], s2 = sinp[t * DH + lane + 64];
    float o1 = y1 * c1 - y2 * s1;
    float o2 = y2 * c2 + y1 * s2;
    unsigned short h, l;
    split2(o1, h, l);
    kh[(size_t)row * DH + lane] = h;
    kl[(size_t)row * DH + lane] = l;
    split2(o2, h, l);
    kh[(size_t)row * DH + lane + 64] = h;
    kl[(size_t)row * DH + lane + 64] = l;
  } else {
    vh[(size_t)row * DH + lane] = f2bf(y1);
    vh[(size_t)row * DH + lane + 64] = f2bf(y2);
  }
}

// ---------------- Flash attention: QBLK=96, 6 waves; fused Q rms+rope; setprio ----------------
// Work-complementary block pairing: per XCD, slot j<32 runs head 2x with qt in
// ascending-work order (qt=(j>>1)+(j&1)*16); slot j>=32 runs head 2x+1 in the
// REVERSE order, so co-resident block pairs on a CU have complementary KV-span
// work (makespan 70 -> 51 tiles model; identical per-block numerics).
template <int WRITE_LO>
__global__ __launch_bounds__(384) void attn3(const float* __restrict__ Qf,
                                             const float* __restrict__ qnw,
                                             const float* __restrict__ cosp,
                                             const float* __restrict__ sinp,
                                             const unsigned short* __restrict__ Kh,
                                             const unsigned short* __restrict__ Kl,
                                             const unsigned short* __restrict__ Vth,
                                             unsigned short* __restrict__ Oh,
                                             unsigned short* __restrict__ Ol,
                                             const int* __restrict__ cu, int ncu) {
  __shared__ unsigned short kh_lds[32][136];
  __shared__ unsigned short kl_lds[32][136];
  __shared__ unsigned short vh_lds[144][40];
  __shared__ unsigned short ph_lds[6][16][40];

  int id = blockIdx.y * gridDim.x + blockIdx.x;
  int xcd = id & 7;
  int j = id >> 3;              // 0..63 within this XCD
  int qt, h;
  if (j < 32) {
    qt = (j >> 1) + ((j & 1) << 4);
    h = 2 * xcd;
  } else {
    int k = 63 - j;             // 31..0
    qt = (k >> 1) + ((k & 1) << 4);
    h = 2 * xcd + 1;
  }
  const int qbase = qt * 96;
  const int kvh = h >> 1;
  const int tid = threadIdx.x, lane = tid & 63, wave = tid >> 6;
  const int g = lane >> 4, r16 = lane & 15;

  for (int i = tid; i < 16 * 40; i += 384) {
    int rr = i / 40, cc = i % 40;
    vh_lds[128 + rr][cc] = (rr == 0) ? (unsigned short)0x3F80 : (unsigned short)0;
  }

  bf16x8 aqh[4], aql[4];
  {
    int q_r = qbase + wave * 16 + r16;
    const float* xq = Qf + (size_t)q_r * HIDDEN + h * DH;
    float xv[4][8];
    float ss = 0.f;
#pragma unroll
    for (int ks = 0; ks < 4; ++ks) {
      f32x4 a = *(const f32x4*)(xq + ks * 32 + g * 8);
      f32x4 b = *(const f32x4*)(xq + ks * 32 + g * 8 + 4);
#pragma unroll
      for (int jj = 0; jj < 4; ++jj) { xv[ks][jj] = a[jj]; xv[ks][4 + jj] = b[jj]; }
#pragma unroll
      for (int jj = 0; jj < 8; ++jj) ss += xv[ks][jj] * xv[ks][jj];
    }
    ss += __shfl_xor(ss, 16, 64);
    ss += __shfl_xor(ss, 32, 64);
    float inv = rsqrtf(ss * (1.0f / 128.0f) + 1e-6f);
    float y[4][8];
#pragma unroll
    for (int ks = 0; ks < 4; ++ks) {
      f32x4 w0 = *(const f32x4*)(qnw + ks * 32 + g * 8);
      f32x4 w1 = *(const f32x4*)(qnw + ks * 32 + g * 8 + 4);
#pragma unroll
      for (int jj = 0; jj < 4; ++jj) {
        y[ks][jj] = xv[ks][jj] * inv * w0[jj];
        y[ks][4 + jj] = xv[ks][4 + jj] * inv * w1[jj];
      }
    }
    const float* cb = cosp + (size_t)q_r * DH;
    const float* sb = sinp + (size_t)q_r * DH;
#pragma unroll
    for (int ks = 0; ks < 4; ++ks) {
      bf16x8 th, tl;
#pragma unroll
      for (int j2 = 0; j2 < 2; ++j2) {
        int col = ks * 32 + g * 8 + j2 * 4;
        f32x4 cv = *(const f32x4*)(cb + col);
        f32x4 sv = *(const f32x4*)(sb + col);
#pragma unroll
        for (int jj = 0; jj < 4; ++jj) {
          float o;
          if (ks < 2) o = y[ks][j2 * 4 + jj] * cv[jj] - y[ks + 2][j2 * 4 + jj] * sv[jj];
          else        o = y[ks][j2 * 4 + jj] * cv[jj] + y[ks - 2][j2 * 4 + jj] * sv[jj];
          unsigned short hx, lx;
          split2(o, hx, lx);
          th[j2 * 4 + jj] = (short)hx;
          tl[j2 * 4 + jj] = (short)lx;
        }
      }
      aqh[ks] = th; aql[ks] = tl;
    }
  }

  int ssr[4];
#pragma unroll
  for (int r = 0; r < 4; ++r) {
    int q_r = qbase + wave * 16 + g * 4 + r;
    int s = 0;
    for (int i = 1; i < ncu; ++i) { int v = cu[i]; if (v <= q_r) s = v; }
    ssr[r] = s;
  }
  int ss_base = 0;
  for (int i = 1; i < ncu; ++i) { int v = cu[i]; if (v <= qbase) ss_base = v; }

  float m_r[4] = {-1e30f, -1e30f, -1e30f, -1e30f};
  f32x4 oacc[8];
#pragma unroll
  for (int db = 0; db < 8; ++db) oacc[db] = (f32x4){0.f, 0.f, 0.f, 0.f};
  f32x4 oaccL = (f32x4){0.f, 0.f, 0.f, 0.f};

  int lo = qbase - WINDOW + 1;
  if (lo < ss_base) lo = ss_base;
  if (lo < 0) lo = 0;
  int kt0 = lo & ~31;
  int ktend = qbase + 95;

  const bool stager = tid < 256;
  const int krow = (tid & 255) >> 3, kc = tid & 7;
  const int vd = (tid & 255) >> 1, vhalf = (tid & 1) * 16;
  const int qmin = qbase + wave * 16;
  const int sw0 = ((kc + 2 * (krow & 15)) & 15) * 16;
  const int sw1 = ((kc + 8 + 2 * (krow & 15)) & 15) * 16;

  ushort8 rkh0, rkh1, rkl0, rkl1, rvh0, rvh1;
  auto loadTile = [&](int kt) {
    if (!stager) return;
    size_t goff = ((size_t)(kt + krow) * NHKV + kvh) * DH + kc * 8;
    rkh0 = *(const ushort8*)(Kh + goff);
    rkh1 = *(const ushort8*)(Kh + goff + 64);
    rkl0 = *(const ushort8*)(Kl + goff);
    rkl1 = *(const ushort8*)(Kl + goff + 64);
    size_t voff = ((size_t)kvh * DH + vd) * T_TOK + kt + vhalf;
    rvh0 = *(const ushort8*)(Vth + voff);
    rvh1 = *(const ushort8*)(Vth + voff + 8);
  };
  auto writeTile = [&]() {
    if (!stager) return;
    char* kbh = (char*)&kh_lds[krow][0];
    char* kbl = (char*)&kl_lds[krow][0];
    *(ushort8*)(kbh + sw0) = rkh0;
    *(ushort8*)(kbh + sw1) = rkh1;
    *(ushort8*)(kbl + sw0) = rkl0;
    *(ushort8*)(kbl + sw1) = rkl1;
    *(ushort8*)&vh_lds[vd][vhalf] = rvh0;
    *(ushort8*)&vh_lds[vd][vhalf + 8] = rvh1;
  };

  loadTile(kt0);
  writeTile();
  __syncthreads();

  for (int kt = kt0; kt <= ktend; kt += 32) {
    const bool hasNext = (kt + 32 <= ktend);
    if (hasNext) loadTile(kt + 32);

    f32x4 s0 = (f32x4){0.f, 0.f, 0.f, 0.f}, s1 = (f32x4){0.f, 0.f, 0.f, 0.f};
    {
      const char* kb0h = (const char*)&kh_lds[r16][0];
      const char* kb1h = (const char*)&kh_lds[16 + r16][0];
      const char* kb0l = (const char*)&kl_lds[r16][0];
      const char* kb1l = (const char*)&kl_lds[16 + r16][0];
      __builtin_amdgcn_s_setprio(1);
#pragma unroll
      for (int ks = 0; ks < 4; ++ks) {
        int sl = ((ks * 4 + g + 2 * r16) & 15) * 16;
        bf16x8 bh0 = *(const bf16x8*)(kb0h + sl);
        bf16x8 bh1 = *(const bf16x8*)(kb1h + sl);
        bf16x8 bl0 = *(const bf16x8*)(kb0l + sl);
        bf16x8 bl1 = *(const bf16x8*)(kb1l + sl);
        s0 = __builtin_amdgcn_mfma_f32_16x16x32_bf16(aqh[ks], bh0, s0, 0, 0, 0);
        s0 = __builtin_amdgcn_mfma_f32_16x16x32_bf16(aqh[ks], bl0, s0, 0, 0, 0);
        s0 = __builtin_amdgcn_mfma_f32_16x16x32_bf16(aql[ks], bh0, s0, 0, 0, 0);
        s1 = __builtin_amdgcn_mfma_f32_16x16x32_bf16(aqh[ks], bh1, s1, 0, 0, 0);
        s1 = __builtin_amdgcn_mfma_f32_16x16x32_bf16(aqh[ks], bl1, s1, 0, 0, 0);
        s1 = __builtin_amdgcn_mfma_f32_16x16x32_bf16(aql[ks], bh1, s1, 0, 0, 0);
      }
      __builtin_amdgcn_s_setprio(0);
    }

    float sv0_[4], sv1_[4], mt_[4];
    bool ok0_[4], ok1_[4];
    bool interior = (kt + 31 <= qmin) && (kt >= qmin + 16 - WINDOW) &&
                    __all(kt >= ssr[3]);
    if (interior) {
#pragma unroll
      for (int r = 0; r < 4; ++r) {
        ok0_[r] = ok1_[r] = true;
        sv0_[r] = s0[r]; sv1_[r] = s1[r];
      }
    } else {
#pragma unroll
      for (int r = 0; r < 4; ++r) {
        int q_r = qmin + g * 4 + r;
        int k0 = kt + r16, k1 = k0 + 16;
        ok0_[r] = (k0 <= q_r) && (k0 > q_r - WINDOW) && (k0 >= ssr[r]);
        ok1_[r] = (k1 <= q_r) && (k1 > q_r - WINDOW) && (k1 >= ssr[r]);
        sv0_[r] = ok0_[r] ? s0[r] : -1e30f;
        sv1_[r] = ok1_[r] ? s1[r] : -1e30f;
      }
    }
#pragma unroll
    for (int r = 0; r < 4; ++r) {
      float mt = fmaxf(sv0_[r], sv1_[r]);
#pragma unroll
      for (int mm = 1; mm < 16; mm <<= 1) mt = fmaxf(mt, __shfl_xor(mt, mm, 64));
      mt_[r] = mt;
    }
    float grow = fmaxf(fmaxf(mt_[0] - m_r[0], mt_[1] - m_r[1]),
                       fmaxf(mt_[2] - m_r[2], mt_[3] - m_r[3]));
    if (!__all(grow <= 8.0f)) {
#pragma unroll
      for (int r = 0; r < 4; ++r) {
        float mnew = fmaxf(m_r[r], mt_[r]);
        float alpha = __expf(m_r[r] - mnew);
        m_r[r] = mnew;
#pragma unroll
        for (int db = 0; db < 8; ++db) oacc[db][r] *= alpha;
        oaccL[r] *= alpha;
      }
    }
#pragma unroll
    for (int r = 0; r < 4; ++r) {
      float p0v = ok0_[r] ? __expf(sv0_[r] - m_r[r]) : 0.f;
      float p1v = ok1_[r] ? __expf(sv1_[r] - m_r[r]) : 0.f;
      ph_lds[wave][g * 4 + r][r16] = f2bf(p0v);
      ph_lds[wave][g * 4 + r][16 + r16] = f2bf(p1v);
    }

    bf16x8 pah = *(const bf16x8*)&ph_lds[wave][r16][g * 8];
    __builtin_amdgcn_s_setprio(1);
#pragma unroll
    for (int db = 0; db < 8; ++db) {
      bf16x8 vfh = *(const bf16x8*)&vh_lds[db * 16 + r16][g * 8];
      oacc[db] = __builtin_amdgcn_mfma_f32_16x16x32_bf16(pah, vfh, oacc[db], 0, 0, 0);
    }
    {
      bf16x8 vfo = *(const bf16x8*)&vh_lds[128 + r16][g * 8];
      oaccL = __builtin_amdgcn_mfma_f32_16x16x32_bf16(pah, vfo, oaccL, 0, 0, 0);
    }
    __builtin_amdgcn_s_setprio(0);

    __syncthreads();
    if (hasNext) writeTile();
    __syncthreads();
  }

#pragma unroll
  for (int r = 0; r < 4; ++r) {
    int q_r = qbase + wave * 16 + g * 4 + r;
    float lsum = __shfl(oaccL[r], lane & 48, 64);
    float invl = 1.f / lsum;
#pragma unroll
    for (int db = 0; db < 8; ++db) {
      float ov = oacc[db][r] * invl;
      unsigned short hh, ll;
      split2(ov, hh, ll);
      Oh[(size_t)q_r * (NHQ * DH) + h * DH + db * 16 + r16] = hh;
      if (WRITE_LO) Ol[(size_t)q_r * (NHQ * DH) + h * DH + db * 16 + r16] = ll;
    }
  }
}

extern "C" void kernel_launch(void* const* d_in, const int* in_sizes, int n_in,
                              void* d_out, int out_size, void* d_ws, size_t ws_size,
                              hipStream_t stream) {
  const float* hidden = (const float*)d_in[0];
  const float* cosp   = (const float*)d_in[1];
  const float* sinp   = (const float*)d_in[2];
  const float* wq0    = (const float*)d_in[3];
  const float* wk0    = (const float*)d_in[4];
  const float* wv0    = (const float*)d_in[5];
  const float* wo0    = (const float*)d_in[6];
  const float* qn0    = (const float*)d_in[7];
  const float* kn0    = (const float*)d_in[8];
  const float* wq1    = (const float*)d_in[9];
  const float* wo1    = (const float*)d_in[10];
  const float* qn1    = (const float*)d_in[11];
  const int*   cu     = (const int*)d_in[12];
  int ncu = in_sizes[12];
  (void)n_in; (void)out_size; (void)ws_size;

  char* p = (char*)d_ws;
  auto alloc = [&](size_t bytes) { char* r = p; p += (bytes + 255) & ~255ull; return r; };

  unsigned short* wqkvh = (unsigned short*)alloc((size_t)2 * HIDDEN * HIDDEN * 2);
  unsigned short* wqkvl = (unsigned short*)alloc((size_t)2 * HIDDEN * HIDDEN * 2);
  unsigned short* wo0sh = (unsigned short*)alloc((size_t)HIDDEN * HIDDEN * 2);
  unsigned short* wo0sl = (unsigned short*)alloc((size_t)HIDDEN * HIDDEN * 2);
  unsigned short* wq1th = (unsigned short*)alloc((size_t)HIDDEN * HIDDEN * 2);
  unsigned short* wq1tl = (unsigned short*)alloc((size_t)HIDDEN * HIDDEN * 2);
  unsigned short* wo1t  = (unsigned short*)alloc((size_t)HIDDEN * HIDDEN * 2);
  float*          c32q  = (float*)alloc((size_t)T_TOK * HIDDEN * 4);
  float*          c32kv = (float*)alloc((size_t)T_TOK * HIDDEN * 4);
  unsigned short* xh    = (unsigned short*)alloc((size_t)T_TOK * HIDDEN * 2);
  unsigned short* xl    = (unsigned short*)alloc((size_t)T_TOK * HIDDEN * 2);
  unsigned short* kh    = (unsigned short*)alloc((size_t)T_TOK * KVN * 2);
  unsigned short* kl    = (unsigned short*)alloc((size_t)T_TOK * KVN * 2);
  unsigned short* vh    = (unsigned short*)alloc((size_t)T_TOK * KVN * 2);
  unsigned short* vth   = (unsigned short*)alloc((size_t)T_TOK * KVN * 2);

  unsigned short* W01th = (unsigned short*)c32q;
  unsigned short* W01tl = W01th + (size_t)HIDDEN * HIDDEN;

  prep<<<26624, 256, 0, stream>>>(hidden, wq0, wk0, wv0, wo0, wq1, wo1,
                                  xh, xl, wqkvh, wqkvl, wo0sh, wo0sl, wq1th, wq1tl, wo1t);

  gemm3_128<<<dim3(T_TOK / 128, 4096 / 128), 256, 0, stream>>>(
      xh, xl, wqkvh, wqkvl, c32q, c32kv, HIDDEN, T_TOK, 4096, HIDDEN);

  rms_kv<<<2 * T_TOK * NHKV / 4, 256, 0, stream>>>(c32kv, kn0, cosp, sinp, kh, kl, vh);
  transpose_u16<<<dim3(KVN / 32, T_TOK / 32), 256, 0, stream>>>(vh, vth, T_TOK, KVN);

  attn3<1><<<dim3(32, 16), 384, 0, stream>>>(c32q, qn0, cosp, sinp, kh, kl, vth, xh, xl, cu, ncu);

  gemm3_64<<<dim3(HIDDEN / 64, HIDDEN / 128), 256, 0, stream>>>(
      wq1th, wq1tl, wo0sh, wo0sl, W01th, W01tl, HIDDEN, HIDDEN, HIDDEN);

  gemm3_96<<<dim3(T_TOK / 96, HIDDEN / 128), 256, 0, stream>>>(
      xh, xl, W01th, W01tl, c32kv, T_TOK, HIDDEN, HIDDEN);

  attn3<0><<<dim3(32, 16), 384, 0, stream>>>(c32kv, qn1, cosp, sinp, kh, kl, vth, xh, nullptr, cu, ncu);

  gemm1_96<<<dim3(T_TOK / 96, HIDDEN / 128), 256, 0, stream>>>(xh, wo1t, (float*)d_out, T_TOK, HIDDEN, HIDDEN);
}